// Round 9
// baseline (232.847 us; speedup 1.0000x reference)
//
#include <hip/hip_runtime.h>
#include <hip/hip_bf16.h>
#include <math.h>

#define BATCH 4
#define N 2048
#define D 256
#define NH 4
#define DH 64
#define TOPK 9
#define NEG_BIG -1e30f

typedef __bf16 bf16;
typedef __bf16 bf16x8 __attribute__((ext_vector_type(8)));
typedef float f32x4 __attribute__((ext_vector_type(4)));

#define PK3(a,b,c) ((a) | ((b) << 2) | ((c) << 4))
#define PK6(a,b,c,d,e,f) ((a) | ((b) << 2) | ((c) << 4) | ((d) << 6) | ((e) << 8) | ((f) << 10))

// s_waitcnt with ONLY vmcnt=N (lgkmcnt=15/expcnt=7 = no wait). gfx9 encoding:
// vmcnt[3:0]@0, expcnt@4, lgkmcnt@8, vmcnt[5:4]@14.
#define WAITVM(Nc) __builtin_amdgcn_s_waitcnt((((Nc) & 0xf)) | (7u << 4) | (0xfu << 8) | ((((unsigned)(Nc)) >> 4) << 14))

__device__ __forceinline__ void async_cp16(const bf16* g, const bf16* l) {
  __builtin_amdgcn_global_load_lds(
      (const __attribute__((address_space(1))) void*)(uintptr_t)g,
      (__attribute__((address_space(3))) void*)(uintptr_t)l, 16, 0, 0);
}

// ---------------------------------------------------------------------------
// prep: blk<8192: x -> XsN (L2-norm, 3-way split, stride 768)
//       blk>=8192: W{q,k,v,o} -> Wt (transpose + 2-way split)
// ---------------------------------------------------------------------------
__global__ __launch_bounds__(64) void prep_xn_w_kernel(const float* __restrict__ x,
                                                       const float* __restrict__ Wq,
                                                       const float* __restrict__ Wk,
                                                       const float* __restrict__ Wv,
                                                       const float* __restrict__ Wo,
                                                       bf16* __restrict__ XsN,
                                                       bf16* __restrict__ Wt) {
  int blk = blockIdx.x;
  int lane = threadIdx.x;
  if (blk < 8192) {
    float4 v = *(const float4*)(x + (size_t)blk * D + lane * 4);
    float ss = v.x * v.x + v.y * v.y + v.z * v.z + v.w * v.w;
    for (int off = 32; off; off >>= 1) ss += __shfl_down(ss, off);
    ss = __shfl(ss, 0);
    float sc = 1.0f / fmaxf(sqrtf(ss), 1e-12f);
    float xs[4] = {v.x * sc, v.y * sc, v.z * sc, v.w * sc};
    bf16* o = XsN + (size_t)blk * 768 + lane * 4;
#pragma unroll
    for (int j = 0; j < 4; ++j) {
      float xv = xs[j];
      bf16 h = (bf16)xv;
      float r1 = xv - (float)h;
      bf16 m = (bf16)r1;
      o[j] = h;
      o[256 + j] = m;
      o[512 + j] = (bf16)(r1 - (float)m);
    }
  } else {
    int jj = blk - 8192;
    const float* W = (jj < 256) ? Wq : (jj < 512) ? Wk : (jj < 768) ? Wv : Wo;
    int j = jj & 255;
    bf16* dst = Wt + (size_t)jj * 512;
    for (int k = lane; k < 256; k += 64) {
      float w = W[(size_t)k * D + j];
      bf16 h = (bf16)w;
      dst[k] = h;
      dst[256 + k] = (bf16)(w - (float)h);
    }
  }
}

// prep phase 2: x -> XsRaw (2-way split, stride 512) — runs after sim is dead
__global__ __launch_bounds__(64) void prep_raw_kernel(const float* __restrict__ x,
                                                      bf16* __restrict__ XsRaw) {
  int row = blockIdx.x;
  int lane = threadIdx.x;
  float4 v = *(const float4*)(x + (size_t)row * D + lane * 4);
  float xs[4] = {v.x, v.y, v.z, v.w};
  bf16* o = XsRaw + (size_t)row * 512 + lane * 4;
#pragma unroll
  for (int j = 0; j < 4; ++j) {
    bf16 h = (bf16)xs[j];
    o[j] = h;
    o[256 + j] = (bf16)(xs[j] - (float)h);
  }
}

// ---------------------------------------------------------------------------
// MFMA GEMM, BK=32 (LDS 32 KB/block -> 5 blocks/CU, all blocks co-resident),
// global_load_lds staging, LDS double-buffer, raw s_barrier + vmcnt(4).
// nsteps = number of BK=32 steps (8 per K=256 chunk).
// mode 0: generic C = A@B^T, grid (Nc/128, M/128, batches).
// mode 1: symmetric sim = A@A^T, grid (544,1,1), XCD-aware triangular decode;
//         nontemporal C stores (incl. mirror).
// ---------------------------------------------------------------------------
__global__ __launch_bounds__(256) void gemm_bt_kernel(const bf16* __restrict__ A,
                                                      const bf16* __restrict__ B,
                                                      float* __restrict__ C,
                                                      int lda, int ldb, int ldc,
                                                      int nsteps, int amap, int bmap,
                                                      long sA, long sB, long sC,
                                                      int mode) {
  __shared__ bf16 As[2][128 * 32];
  __shared__ bf16 Bs[2][128 * 32];
  int tid = threadIdx.x;
  int lane = tid & 63;
  int wv = tid >> 6;
  int wm = (wv >> 1) * 64;
  int wn = (wv & 1) * 64;
  int bx, by, z;
  if (mode) {  // XCD-aware triangular decode
    int g = blockIdx.x;
    int xcd = g & 7;
    int slot = g >> 3;          // 0..67
    z = xcd >> 1;
    int t = (xcd & 1) * 68 + slot;  // pair 0..135
    by = 0;
    while (t >= 16 - by) { t -= 16 - by; ++by; }
    bx = by + t;
  } else {
    bx = blockIdx.x;
    by = blockIdx.y;
    z = blockIdx.z;
  }
  int row0 = by * 128;
  int col0 = bx * 128;
  const bf16* Ab = A + (size_t)z * sA + (size_t)row0 * lda;
  const bf16* Bb = B + (size_t)z * sB + (size_t)col0 * ldb;
  float* Cb = C + (size_t)z * sC;

  // staging: instr q in 0..1 per matrix; slot = q*256+tid covers
  // row = q*64 + (tid>>2), granule = tid&3; fetch physical granule
  // (tid&3)^(row&3) -> swizzled LDS layout, conflict-balanced frag reads.
  int rth = tid >> 2;                  // 0..63
  int gperm = (tid & 3) ^ (rth & 3);
  const bf16* ga0 = Ab + (size_t)rth * lda + gperm * 8;
  const bf16* gb0 = Bb + (size_t)rth * ldb + gperm * 8;
  int ldsoff = tid * 8;  // 16 B per thread per instr

  int fr = lane & 15;
  int G = lane >> 4;       // logical granule 0..3 (k-offset = G*8)

  f32x4 acc[4][4] = {};

  auto issue = [&](int st, int buf) {
    int ch = st >> 3;
    int aoff = (((amap >> (ch * 2)) & 3) << 8) | ((st & 7) << 5);
    int boff = (((bmap >> (ch * 2)) & 3) << 8) | ((st & 7) << 5);
#pragma unroll
    for (int q = 0; q < 2; ++q)
      async_cp16(ga0 + (size_t)q * 64 * lda + aoff, &As[buf][ldsoff + q * 2048]);
#pragma unroll
    for (int q = 0; q < 2; ++q)
      async_cp16(gb0 + (size_t)q * 64 * ldb + boff, &Bs[buf][ldsoff + q * 2048]);
  };

  issue(0, 0);
  for (int st = 0; st < nsteps; ++st) {
    int buf = st & 1;
    if (st + 1 < nsteps) {
      issue(st + 1, buf ^ 1);
      WAITVM(4);   // in-order retire: <=4 outstanding => buf st fully landed
    } else {
      WAITVM(0);
    }
    __builtin_amdgcn_s_barrier();  // all waves' staging for buf visible
    bf16x8 af[4], bfr[4];
#pragma unroll
    for (int mi = 0; mi < 4; ++mi) {
      int r = wm + mi * 16 + fr;
      af[mi] = *(const bf16x8*)&As[buf][r * 32 + ((G ^ (r & 3)) << 3)];
    }
#pragma unroll
    for (int nj = 0; nj < 4; ++nj) {
      int r = wn + nj * 16 + fr;
      bfr[nj] = *(const bf16x8*)&Bs[buf][r * 32 + ((G ^ (r & 3)) << 3)];
    }
#pragma unroll
    for (int mi = 0; mi < 4; ++mi)
#pragma unroll
      for (int nj = 0; nj < 4; ++nj)
        acc[mi][nj] = __builtin_amdgcn_mfma_f32_16x16x32_bf16(af[mi], bfr[nj], acc[mi][nj], 0, 0, 0);
    __builtin_amdgcn_s_barrier();  // reads of buf done before st+2 overwrites it
  }

  int er = (lane >> 4) * 4;
  int ec = lane & 15;
#pragma unroll
  for (int mi = 0; mi < 4; ++mi)
#pragma unroll
    for (int nj = 0; nj < 4; ++nj) {
      int rb = row0 + wm + mi * 16 + er;
      int cb = col0 + wn + nj * 16 + ec;
      if (mode) {
#pragma unroll
        for (int reg = 0; reg < 4; ++reg)
          __builtin_nontemporal_store(acc[mi][nj][reg],
                                      &Cb[(size_t)(rb + reg) * ldc + cb]);
        if (bx != by) {
#pragma unroll
          for (int reg = 0; reg < 4; ++reg)
            __builtin_nontemporal_store(acc[mi][nj][reg],
                                        &Cb[(size_t)cb * ldc + rb + reg]);
        }
      } else {
#pragma unroll
        for (int reg = 0; reg < 4; ++reg)
          Cb[(size_t)(rb + reg) * ldc + cb] = acc[mi][nj][reg];
      }
    }
}

// ---------------------------------------------------------------------------
// top-9 per row by 9x extract-max (branch-free masked argmax in registers),
// fused adjacency write. One wave per row; mask pre-zeroed.
// Selection set identical to lax.top_k: (value desc, index asc) tie-break.
// ---------------------------------------------------------------------------
__global__ __launch_bounds__(64) void topk_adj_kernel(const float* __restrict__ sim,
                                                      unsigned* __restrict__ mask) {
  int row = blockIdx.x;
  int lane = threadIdx.x;
  int b = row >> 11, r = row & 2047;
  const float* srow = sim + (size_t)row * N;
  float v[32];
#pragma unroll
  for (int it = 0; it < 8; ++it) {
    float4 q = *(const float4*)(srow + it * 256 + lane * 4);
    v[it * 4 + 0] = q.x; v[it * 4 + 1] = q.y;
    v[it * 4 + 2] = q.z; v[it * 4 + 3] = q.w;
  }
  unsigned removed = 0;
  for (int rs = 0; rs < TOPK; ++rs) {
    float m = -3e38f;
    int mi = 0;
#pragma unroll
    for (int i = 0; i < 32; ++i) {
      float vv = ((removed >> i) & 1u) ? -3e38f : v[i];
      if (vv > m) { m = vv; mi = i; }  // ascending i = ascending global idx
    }
    int gidx = ((mi >> 2) << 8) + lane * 4 + (mi & 3);
    for (int off = 32; off; off >>= 1) {
      float om = __shfl_down(m, off);
      int og = __shfl_down(gidx, off);
      if (om > m || (om == m && og < gidx)) { m = om; gidx = og; }
    }
    gidx = __shfl(gidx, 0);
    if (((gidx >> 2) & 63) == lane)
      removed |= 1u << (((gidx >> 8) << 2) | (gidx & 3));
    if (lane == 0) {
      atomicOr(&mask[(size_t)row * 64 + (gidx >> 5)], 1u << (gidx & 31));
      atomicOr(&mask[(((size_t)b << 11) + gidx) * 64 + (r >> 5)], 1u << (r & 31));
    }
  }
}

// ---------------------------------------------------------------------------
// sparse attention: 4 waves/block, one (b,n) row per wave; writes bf16-split
// aos (stride 512) directly.
// ---------------------------------------------------------------------------
__global__ __launch_bounds__(256) void attn_kernel(const float* __restrict__ qkv,
                                                   const unsigned* __restrict__ mask,
                                                   bf16* __restrict__ aos) {
  __shared__ float sq[4][256];
  __shared__ unsigned short nbr[4][2048];
  __shared__ int s_nn[4];
  int wv = threadIdx.x >> 6;
  int lane = threadIdx.x & 63;
  int bn = blockIdx.x * 4 + wv;
  int b = bn >> 11;
  if (lane == 0) s_nn[wv] = 0;
  *(float4*)&sq[wv][lane * 4] = *(const float4*)(qkv + (size_t)bn * 768 + lane * 4);
  __syncthreads();
  unsigned bits = mask[(size_t)bn * (N / 32) + lane];
  while (bits) {
    int bit = __ffs(bits) - 1;
    bits &= bits - 1;
    int p = atomicAdd(&s_nn[wv], 1);
    nbr[wv][p] = (unsigned short)(lane * 32 + bit);
  }
  __syncthreads();
  int nn = s_nn[wv];
  const float* base = qkv + (size_t)b * N * 768;
  float acc[4] = {0.f, 0.f, 0.f, 0.f};

  auto score4 = [&](int j, float* s) {
    const float* kr = base + (size_t)j * 768 + 256;
#pragma unroll
    for (int h = 0; h < 4; ++h) {
      float a = 0.f;
#pragma unroll
      for (int c = 0; c < DH; c += 4) {
        float4 kk = *(const float4*)(kr + h * DH + c);
        a += sq[wv][h * DH + c] * kk.x + sq[wv][h * DH + c + 1] * kk.y +
             sq[wv][h * DH + c + 2] * kk.z + sq[wv][h * DH + c + 3] * kk.w;
      }
      s[h] = a * 0.125f;
    }
  };

  if (nn <= 64) {
    float s[4] = {NEG_BIG, NEG_BIG, NEG_BIG, NEG_BIG};
    if (lane < nn) score4(nbr[wv][lane], s);
    float w[4], l[4];
#pragma unroll
    for (int h = 0; h < 4; ++h) {
      float m = s[h];
      for (int off = 32; off; off >>= 1) m = fmaxf(m, __shfl_down(m, off));
      m = __shfl(m, 0);
      float e = (lane < nn) ? __expf(s[h] - m) : 0.f;
      float ls = e;
      for (int off = 32; off; off >>= 1) ls += __shfl_down(ls, off);
      l[h] = __shfl(ls, 0);
      w[h] = e;
    }
    int i = 0;
    for (; i + 4 <= nn; i += 4) {
      int j0 = nbr[wv][i + 0], j1 = nbr[wv][i + 1];
      int j2 = nbr[wv][i + 2], j3 = nbr[wv][i + 3];
      const float* p0 = base + (size_t)j0 * 768 + 512;
      const float* p1 = base + (size_t)j1 * 768 + 512;
      const float* p2 = base + (size_t)j2 * 768 + 512;
      const float* p3 = base + (size_t)j3 * 768 + 512;
#pragma unroll
      for (int h = 0; h < 4; ++h) {
        acc[h] += __shfl(w[h], i + 0) * p0[h * DH + lane] +
                  __shfl(w[h], i + 1) * p1[h * DH + lane] +
                  __shfl(w[h], i + 2) * p2[h * DH + lane] +
                  __shfl(w[h], i + 3) * p3[h * DH + lane];
      }
    }
    for (; i < nn; ++i) {
      const float* p0 = base + (size_t)nbr[wv][i] * 768 + 512;
#pragma unroll
      for (int h = 0; h < 4; ++h) acc[h] += __shfl(w[h], i) * p0[h * DH + lane];
    }
#pragma unroll
    for (int h = 0; h < 4; ++h) acc[h] /= l[h];
  } else {
    float m[4] = {NEG_BIG, NEG_BIG, NEG_BIG, NEG_BIG};
    for (int i0 = 0; i0 < nn; i0 += 64) {
      float s[4] = {NEG_BIG, NEG_BIG, NEG_BIG, NEG_BIG};
      if (i0 + lane < nn) score4(nbr[wv][i0 + lane], s);
#pragma unroll
      for (int h = 0; h < 4; ++h) m[h] = fmaxf(m[h], s[h]);
    }
#pragma unroll
    for (int h = 0; h < 4; ++h) {
      for (int off = 32; off; off >>= 1) m[h] = fmaxf(m[h], __shfl_down(m[h], off));
      m[h] = __shfl(m[h], 0);
    }
    float l[4] = {0.f, 0.f, 0.f, 0.f};
    for (int i0 = 0; i0 < nn; i0 += 64) {
      float s[4] = {NEG_BIG, NEG_BIG, NEG_BIG, NEG_BIG};
      if (i0 + lane < nn) score4(nbr[wv][i0 + lane], s);
      float e[4];
#pragma unroll
      for (int h = 0; h < 4; ++h) {
        e[h] = (i0 + lane < nn) ? __expf(s[h] - m[h]) : 0.f;
        float ls = e[h];
        for (int off = 32; off; off >>= 1) ls += __shfl_down(ls, off);
        l[h] += __shfl(ls, 0);
      }
      int lim = min(64, nn - i0);
      for (int ii = 0; ii < lim; ++ii) {
        const float* p0 = base + (size_t)nbr[wv][i0 + ii] * 768 + 512;
#pragma unroll
        for (int h = 0; h < 4; ++h) acc[h] += __shfl(e[h], ii) * p0[h * DH + lane];
      }
    }
#pragma unroll
    for (int h = 0; h < 4; ++h) acc[h] /= l[h];
  }
#pragma unroll
  for (int h = 0; h < 4; ++h) {
    float a = acc[h];
    bf16 hi = (bf16)a;
    aos[(size_t)bn * 512 + h * DH + lane] = hi;
    aos[(size_t)bn * 512 + 256 + h * DH + lane] = (bf16)(a - (float)hi);
  }
}

// ---------------------------------------------------------------------------
// epilogue: u = x + proj + bo; out = LN(u)*gamma + beta
// ---------------------------------------------------------------------------
__global__ __launch_bounds__(64) void ln_kernel(const float* __restrict__ x,
                                                const float* __restrict__ proj,
                                                const float* __restrict__ bo,
                                                const float* __restrict__ gamma,
                                                const float* __restrict__ beta,
                                                float* __restrict__ out) {
  int row = blockIdx.x;
  int lane = threadIdx.x;
  size_t base = (size_t)row * D + lane * 4;
  float4 xv = *(const float4*)(x + base);
  float4 pv = *(const float4*)(proj + base);
  float4 bv = *(const float4*)(bo + lane * 4);
  float u0 = xv.x + pv.x + bv.x, u1 = xv.y + pv.y + bv.y;
  float u2 = xv.z + pv.z + bv.z, u3 = xv.w + pv.w + bv.w;
  float s = u0 + u1 + u2 + u3;
  for (int off = 32; off; off >>= 1) s += __shfl_down(s, off);
  s = __shfl(s, 0);
  float mean = s * (1.0f / D);
  float d0 = u0 - mean, d1 = u1 - mean, d2 = u2 - mean, d3 = u3 - mean;
  float ss = d0 * d0 + d1 * d1 + d2 * d2 + d3 * d3;
  for (int off = 32; off; off >>= 1) ss += __shfl_down(ss, off);
  ss = __shfl(ss, 0);
  float rstd = rsqrtf(ss * (1.0f / D) + 1e-5f);
  float4 gv = *(const float4*)(gamma + lane * 4);
  float4 be = *(const float4*)(beta + lane * 4);
  float4 o;
  o.x = d0 * rstd * gv.x + be.x;
  o.y = d1 * rstd * gv.y + be.y;
  o.z = d2 * rstd * gv.z + be.z;
  o.w = d3 * rstd * gv.w + be.w;
  *(float4*)(out + base) = o;
}

// ---------------------------------------------------------------------------
// Workspace (83,132,416 B total — round-3-proven big layout):
//  phase A: XsN [0,12.58M) | sim [12.58M,79.69M) | mask | Wt
//  phase B (XsN+sim dead): XsRaw [0,8.39M) | qkv [8.39M,33.55M)
//                          aos [33.55M,41.94M) | proj [41.94M,50.33M)
// ---------------------------------------------------------------------------
extern "C" void kernel_launch(void* const* d_in, const int* in_sizes, int n_in,
                              void* d_out, int out_size, void* d_ws, size_t ws_size,
                              hipStream_t stream) {
  const float* x     = (const float*)d_in[0];
  const float* Wq    = (const float*)d_in[1];
  const float* Wk    = (const float*)d_in[2];
  const float* Wv    = (const float*)d_in[3];
  const float* Wo    = (const float*)d_in[4];
  const float* bo    = (const float*)d_in[5];
  const float* gamma = (const float*)d_in[6];
  const float* beta  = (const float*)d_in[7];
  float* out = (float*)d_out;

  char* ws = (char*)d_ws;
  bf16* XsN      = (bf16*)(ws);
  float* sim     = (float*)(ws + 12582912);
  unsigned* mask = (unsigned*)(ws + 79986688);
  bf16* Wt       = (bf16*)(ws + 82083840);
  bf16* XsRaw    = (bf16*)(ws);
  float* qkv     = (float*)(ws + 8388608);
  bf16* aos      = (bf16*)(ws + 33554432);
  float* proj    = (float*)(ws + 41943040);

  const int AMAP_SIM = PK6(0, 1, 0, 1, 0, 2);
  const int BMAP_SIM = PK6(0, 0, 1, 1, 2, 0);
  const int AMAP_2T  = PK3(0, 1, 0);
  const int BMAP_2T  = PK3(0, 0, 1);

  (void)hipMemsetAsync(mask, 0, (size_t)BATCH * N * (N / 32) * sizeof(unsigned), stream);
  prep_xn_w_kernel<<<9216, 64, 0, stream>>>(x, Wq, Wk, Wv, Wo, XsN, Wt);

  gemm_bt_kernel<<<dim3(544, 1, 1), 256, 0, stream>>>(
      XsN, XsN, sim, 768, 768, N, 48, AMAP_SIM, BMAP_SIM,
      (long)N * 768, (long)N * 768, (long)N * N, 1);
  topk_adj_kernel<<<BATCH * N, 64, 0, stream>>>(sim, mask);

  prep_raw_kernel<<<BATCH * N, 64, 0, stream>>>(x, XsRaw);
  gemm_bt_kernel<<<dim3(6, 64, 1), 256, 0, stream>>>(
      XsRaw, Wt, qkv, 512, 512, 768, 16, AMAP_2T, BMAP_2T, 0, 0, 0, 0);

  attn_kernel<<<(BATCH * N) / 4, 256, 0, stream>>>(qkv, mask, aos);

  gemm_bt_kernel<<<dim3(2, 64, 1), 256, 0, stream>>>(
      aos, Wt + (size_t)768 * 512, proj, 512, 512, D, 16, AMAP_2T, BMAP_2T, 0, 0, 0, 0);
  ln_kernel<<<BATCH * N, 64, 0, stream>>>(x, proj, bo, gamma, beta, out);
}

// Round 10
// 231.756 us; speedup vs baseline: 1.0047x; 1.0047x over previous
//
#include <hip/hip_runtime.h>
#include <hip/hip_bf16.h>
#include <math.h>

#define BATCH 4
#define N 2048
#define D 256
#define NH 4
#define DH 64
#define TOPK 9
#define NEG_BIG -1e30f

typedef __bf16 bf16;
typedef __bf16 bf16x8 __attribute__((ext_vector_type(8)));
typedef float f32x4 __attribute__((ext_vector_type(4)));

#define PK3(a,b,c) ((a) | ((b) << 2) | ((c) << 4))
#define PK6(a,b,c,d,e,f) ((a) | ((b) << 2) | ((c) << 4) | ((d) << 6) | ((e) << 8) | ((f) << 10))

// s_waitcnt with ONLY vmcnt=N (lgkmcnt=15/expcnt=7 = no wait). gfx9 encoding:
// vmcnt[3:0]@0, expcnt@4, lgkmcnt@8, vmcnt[5:4]@14.
#define WAITVM(Nc) __builtin_amdgcn_s_waitcnt((((Nc) & 0xf)) | (7u << 4) | (0xfu << 8) | ((((unsigned)(Nc)) >> 4) << 14))

__device__ __forceinline__ void async_cp16(const bf16* g, const bf16* l) {
  __builtin_amdgcn_global_load_lds(
      (const __attribute__((address_space(1))) void*)(uintptr_t)g,
      (__attribute__((address_space(3))) void*)(uintptr_t)l, 16, 0, 0);
}

// ---------------------------------------------------------------------------
// prep: blk<8192: x -> XsN (L2-norm, 3-way split, stride 768)
//       blk>=8192: W{q,k,v,o} -> Wt (transpose + 2-way split)
// ---------------------------------------------------------------------------
__global__ __launch_bounds__(64) void prep_xn_w_kernel(const float* __restrict__ x,
                                                       const float* __restrict__ Wq,
                                                       const float* __restrict__ Wk,
                                                       const float* __restrict__ Wv,
                                                       const float* __restrict__ Wo,
                                                       bf16* __restrict__ XsN,
                                                       bf16* __restrict__ Wt) {
  int blk = blockIdx.x;
  int lane = threadIdx.x;
  if (blk < 8192) {
    float4 v = *(const float4*)(x + (size_t)blk * D + lane * 4);
    float ss = v.x * v.x + v.y * v.y + v.z * v.z + v.w * v.w;
    for (int off = 32; off; off >>= 1) ss += __shfl_down(ss, off);
    ss = __shfl(ss, 0);
    float sc = 1.0f / fmaxf(sqrtf(ss), 1e-12f);
    float xs[4] = {v.x * sc, v.y * sc, v.z * sc, v.w * sc};
    bf16* o = XsN + (size_t)blk * 768 + lane * 4;
#pragma unroll
    for (int j = 0; j < 4; ++j) {
      float xv = xs[j];
      bf16 h = (bf16)xv;
      float r1 = xv - (float)h;
      bf16 m = (bf16)r1;
      o[j] = h;
      o[256 + j] = m;
      o[512 + j] = (bf16)(r1 - (float)m);
    }
  } else {
    int jj = blk - 8192;
    const float* W = (jj < 256) ? Wq : (jj < 512) ? Wk : (jj < 768) ? Wv : Wo;
    int j = jj & 255;
    bf16* dst = Wt + (size_t)jj * 512;
    for (int k = lane; k < 256; k += 64) {
      float w = W[(size_t)k * D + j];
      bf16 h = (bf16)w;
      dst[k] = h;
      dst[256 + k] = (bf16)(w - (float)h);
    }
  }
}

// prep phase 2: x -> XsRaw (2-way split, stride 512) — runs after sim is dead
__global__ __launch_bounds__(64) void prep_raw_kernel(const float* __restrict__ x,
                                                      bf16* __restrict__ XsRaw) {
  int row = blockIdx.x;
  int lane = threadIdx.x;
  float4 v = *(const float4*)(x + (size_t)row * D + lane * 4);
  float xs[4] = {v.x, v.y, v.z, v.w};
  bf16* o = XsRaw + (size_t)row * 512 + lane * 4;
#pragma unroll
  for (int j = 0; j < 4; ++j) {
    bf16 h = (bf16)xs[j];
    o[j] = h;
    o[256 + j] = (bf16)(xs[j] - (float)h);
  }
}

// ---------------------------------------------------------------------------
// MFMA GEMM, BK=32 (LDS 32 KB/block -> 5 blocks/CU, all sim blocks
// co-resident), global_load_lds staging, LDS double-buffer, raw s_barrier +
// vmcnt(4).  Swizzle key = (row>>1)&3: a 16-lane ds_read_b128 phase at fixed
// G hits class (fr&1)*4 + (G^((fr>>1)&3)) -> every 4-bank group exactly 2x
// (2-way = free, m136).  [Round-9's r&3 key gave 4-way = 3.3M conflicts.]
// mode 0: generic C = A@B^T, grid (Nc/128, M/128, batches).
// mode 1: symmetric sim = A@A^T, grid (544,1,1), XCD-aware triangular decode;
//         nontemporal C stores (incl. mirror).
// ---------------------------------------------------------------------------
__global__ __launch_bounds__(256) void gemm_bt_kernel(const bf16* __restrict__ A,
                                                      const bf16* __restrict__ B,
                                                      float* __restrict__ C,
                                                      int lda, int ldb, int ldc,
                                                      int nsteps, int amap, int bmap,
                                                      long sA, long sB, long sC,
                                                      int mode) {
  __shared__ bf16 As[2][128 * 32];
  __shared__ bf16 Bs[2][128 * 32];
  int tid = threadIdx.x;
  int lane = tid & 63;
  int wv = tid >> 6;
  int wm = (wv >> 1) * 64;
  int wn = (wv & 1) * 64;
  int bx, by, z;
  if (mode) {  // XCD-aware triangular decode
    int g = blockIdx.x;
    int xcd = g & 7;
    int slot = g >> 3;          // 0..67
    z = xcd >> 1;
    int t = (xcd & 1) * 68 + slot;  // pair 0..135
    by = 0;
    while (t >= 16 - by) { t -= 16 - by; ++by; }
    bx = by + t;
  } else {
    bx = blockIdx.x;
    by = blockIdx.y;
    z = blockIdx.z;
  }
  int row0 = by * 128;
  int col0 = bx * 128;
  const bf16* Ab = A + (size_t)z * sA + (size_t)row0 * lda;
  const bf16* Bb = B + (size_t)z * sB + (size_t)col0 * ldb;
  float* Cb = C + (size_t)z * sC;

  // staging: instr q in 0..1 per matrix; slot = q*256+tid covers
  // row = q*64 + (tid>>2), physical granule c = tid&3; fetch source granule
  // c ^ ((row>>1)&3)  (q*64 drops out mod 4).
  int rth = tid >> 2;                  // 0..63
  int gperm = (tid & 3) ^ ((rth >> 1) & 3);
  const bf16* ga0 = Ab + (size_t)rth * lda + gperm * 8;
  const bf16* gb0 = Bb + (size_t)rth * ldb + gperm * 8;
  int ldsoff = tid * 8;  // 16 B per thread per instr

  int fr = lane & 15;
  int G = lane >> 4;       // logical granule 0..3 (k-offset = G*8)

  f32x4 acc[4][4] = {};

  auto issue = [&](int st, int buf) {
    int ch = st >> 3;
    int aoff = (((amap >> (ch * 2)) & 3) << 8) | ((st & 7) << 5);
    int boff = (((bmap >> (ch * 2)) & 3) << 8) | ((st & 7) << 5);
#pragma unroll
    for (int q = 0; q < 2; ++q)
      async_cp16(ga0 + (size_t)q * 64 * lda + aoff, &As[buf][ldsoff + q * 2048]);
#pragma unroll
    for (int q = 0; q < 2; ++q)
      async_cp16(gb0 + (size_t)q * 64 * ldb + boff, &Bs[buf][ldsoff + q * 2048]);
  };

  issue(0, 0);
  for (int st = 0; st < nsteps; ++st) {
    int buf = st & 1;
    if (st + 1 < nsteps) {
      issue(st + 1, buf ^ 1);
      WAITVM(4);   // in-order retire: <=4 outstanding => buf st fully landed
    } else {
      WAITVM(0);
    }
    __builtin_amdgcn_s_barrier();  // all waves' staging for buf visible
    bf16x8 af[4], bfr[4];
#pragma unroll
    for (int mi = 0; mi < 4; ++mi) {
      int r = wm + mi * 16 + fr;
      af[mi] = *(const bf16x8*)&As[buf][r * 32 + ((G ^ ((r >> 1) & 3)) << 3)];
    }
#pragma unroll
    for (int nj = 0; nj < 4; ++nj) {
      int r = wn + nj * 16 + fr;
      bfr[nj] = *(const bf16x8*)&Bs[buf][r * 32 + ((G ^ ((r >> 1) & 3)) << 3)];
    }
#pragma unroll
    for (int mi = 0; mi < 4; ++mi)
#pragma unroll
      for (int nj = 0; nj < 4; ++nj)
        acc[mi][nj] = __builtin_amdgcn_mfma_f32_16x16x32_bf16(af[mi], bfr[nj], acc[mi][nj], 0, 0, 0);
    __builtin_amdgcn_s_barrier();  // reads of buf done before st+2 overwrites it
  }

  int er = (lane >> 4) * 4;
  int ec = lane & 15;
#pragma unroll
  for (int mi = 0; mi < 4; ++mi)
#pragma unroll
    for (int nj = 0; nj < 4; ++nj) {
      int rb = row0 + wm + mi * 16 + er;
      int cb = col0 + wn + nj * 16 + ec;
      if (mode) {
#pragma unroll
        for (int reg = 0; reg < 4; ++reg)
          __builtin_nontemporal_store(acc[mi][nj][reg],
                                      &Cb[(size_t)(rb + reg) * ldc + cb]);
        if (bx != by) {
#pragma unroll
          for (int reg = 0; reg < 4; ++reg)
            __builtin_nontemporal_store(acc[mi][nj][reg],
                                        &Cb[(size_t)cb * ldc + rb + reg]);
        }
      } else {
#pragma unroll
        for (int reg = 0; reg < 4; ++reg)
          Cb[(size_t)(rb + reg) * ldc + cb] = acc[mi][nj][reg];
      }
    }
}

// ---------------------------------------------------------------------------
// top-9 per row by 9x extract-max (branch-free masked argmax in registers),
// fused adjacency write. One wave per row; mask pre-zeroed.
// Selection set identical to lax.top_k: (value desc, index asc) tie-break.
// ---------------------------------------------------------------------------
__global__ __launch_bounds__(64) void topk_adj_kernel(const float* __restrict__ sim,
                                                      unsigned* __restrict__ mask) {
  int row = blockIdx.x;
  int lane = threadIdx.x;
  int b = row >> 11, r = row & 2047;
  const float* srow = sim + (size_t)row * N;
  float v[32];
#pragma unroll
  for (int it = 0; it < 8; ++it) {
    float4 q = *(const float4*)(srow + it * 256 + lane * 4);
    v[it * 4 + 0] = q.x; v[it * 4 + 1] = q.y;
    v[it * 4 + 2] = q.z; v[it * 4 + 3] = q.w;
  }
  unsigned removed = 0;
  for (int rs = 0; rs < TOPK; ++rs) {
    float m = -3e38f;
    int mi = 0;
#pragma unroll
    for (int i = 0; i < 32; ++i) {
      float vv = ((removed >> i) & 1u) ? -3e38f : v[i];
      if (vv > m) { m = vv; mi = i; }  // ascending i = ascending global idx
    }
    int gidx = ((mi >> 2) << 8) + lane * 4 + (mi & 3);
    for (int off = 32; off; off >>= 1) {
      float om = __shfl_down(m, off);
      int og = __shfl_down(gidx, off);
      if (om > m || (om == m && og < gidx)) { m = om; gidx = og; }
    }
    gidx = __shfl(gidx, 0);
    if (((gidx >> 2) & 63) == lane)
      removed |= 1u << (((gidx >> 8) << 2) | (gidx & 3));
    if (lane == 0) {
      atomicOr(&mask[(size_t)row * 64 + (gidx >> 5)], 1u << (gidx & 31));
      atomicOr(&mask[(((size_t)b << 11) + gidx) * 64 + (r >> 5)], 1u << (r & 31));
    }
  }
}

// ---------------------------------------------------------------------------
// sparse attention: 4 waves/block, one (b,n) row per wave; writes bf16-split
// aos (stride 512) directly.
// ---------------------------------------------------------------------------
__global__ __launch_bounds__(256) void attn_kernel(const float* __restrict__ qkv,
                                                   const unsigned* __restrict__ mask,
                                                   bf16* __restrict__ aos) {
  __shared__ float sq[4][256];
  __shared__ unsigned short nbr[4][2048];
  __shared__ int s_nn[4];
  int wv = threadIdx.x >> 6;
  int lane = threadIdx.x & 63;
  int bn = blockIdx.x * 4 + wv;
  int b = bn >> 11;
  if (lane == 0) s_nn[wv] = 0;
  *(float4*)&sq[wv][lane * 4] = *(const float4*)(qkv + (size_t)bn * 768 + lane * 4);
  __syncthreads();
  unsigned bits = mask[(size_t)bn * (N / 32) + lane];
  while (bits) {
    int bit = __ffs(bits) - 1;
    bits &= bits - 1;
    int p = atomicAdd(&s_nn[wv], 1);
    nbr[wv][p] = (unsigned short)(lane * 32 + bit);
  }
  __syncthreads();
  int nn = s_nn[wv];
  const float* base = qkv + (size_t)b * N * 768;
  float acc[4] = {0.f, 0.f, 0.f, 0.f};

  auto score4 = [&](int j, float* s) {
    const float* kr = base + (size_t)j * 768 + 256;
#pragma unroll
    for (int h = 0; h < 4; ++h) {
      float a = 0.f;
#pragma unroll
      for (int c = 0; c < DH; c += 4) {
        float4 kk = *(const float4*)(kr + h * DH + c);
        a += sq[wv][h * DH + c] * kk.x + sq[wv][h * DH + c + 1] * kk.y +
             sq[wv][h * DH + c + 2] * kk.z + sq[wv][h * DH + c + 3] * kk.w;
      }
      s[h] = a * 0.125f;
    }
  };

  if (nn <= 64) {
    float s[4] = {NEG_BIG, NEG_BIG, NEG_BIG, NEG_BIG};
    if (lane < nn) score4(nbr[wv][lane], s);
    float w[4], l[4];
#pragma unroll
    for (int h = 0; h < 4; ++h) {
      float m = s[h];
      for (int off = 32; off; off >>= 1) m = fmaxf(m, __shfl_down(m, off));
      m = __shfl(m, 0);
      float e = (lane < nn) ? __expf(s[h] - m) : 0.f;
      float ls = e;
      for (int off = 32; off; off >>= 1) ls += __shfl_down(ls, off);
      l[h] = __shfl(ls, 0);
      w[h] = e;
    }
    int i = 0;
    for (; i + 4 <= nn; i += 4) {
      int j0 = nbr[wv][i + 0], j1 = nbr[wv][i + 1];
      int j2 = nbr[wv][i + 2], j3 = nbr[wv][i + 3];
      const float* p0 = base + (size_t)j0 * 768 + 512;
      const float* p1 = base + (size_t)j1 * 768 + 512;
      const float* p2 = base + (size_t)j2 * 768 + 512;
      const float* p3 = base + (size_t)j3 * 768 + 512;
#pragma unroll
      for (int h = 0; h < 4; ++h) {
        acc[h] += __shfl(w[h], i + 0) * p0[h * DH + lane] +
                  __shfl(w[h], i + 1) * p1[h * DH + lane] +
                  __shfl(w[h], i + 2) * p2[h * DH + lane] +
                  __shfl(w[h], i + 3) * p3[h * DH + lane];
      }
    }
    for (; i < nn; ++i) {
      const float* p0 = base + (size_t)nbr[wv][i] * 768 + 512;
#pragma unroll
      for (int h = 0; h < 4; ++h) acc[h] += __shfl(w[h], i) * p0[h * DH + lane];
    }
#pragma unroll
    for (int h = 0; h < 4; ++h) acc[h] /= l[h];
  } else {
    float m[4] = {NEG_BIG, NEG_BIG, NEG_BIG, NEG_BIG};
    for (int i0 = 0; i0 < nn; i0 += 64) {
      float s[4] = {NEG_BIG, NEG_BIG, NEG_BIG, NEG_BIG};
      if (i0 + lane < nn) score4(nbr[wv][i0 + lane], s);
#pragma unroll
      for (int h = 0; h < 4; ++h) m[h] = fmaxf(m[h], s[h]);
    }
#pragma unroll
    for (int h = 0; h < 4; ++h) {
      for (int off = 32; off; off >>= 1) m[h] = fmaxf(m[h], __shfl_down(m[h], off));
      m[h] = __shfl(m[h], 0);
    }
    float l[4] = {0.f, 0.f, 0.f, 0.f};
    for (int i0 = 0; i0 < nn; i0 += 64) {
      float s[4] = {NEG_BIG, NEG_BIG, NEG_BIG, NEG_BIG};
      if (i0 + lane < nn) score4(nbr[wv][i0 + lane], s);
      float e[4];
#pragma unroll
      for (int h = 0; h < 4; ++h) {
        e[h] = (i0 + lane < nn) ? __expf(s[h] - m[h]) : 0.f;
        float ls = e[h];
        for (int off = 32; off; off >>= 1) ls += __shfl_down(ls, off);
        l[h] += __shfl(ls, 0);
      }
      int lim = min(64, nn - i0);
      for (int ii = 0; ii < lim; ++ii) {
        const float* p0 = base + (size_t)nbr[wv][i0 + ii] * 768 + 512;
#pragma unroll
        for (int h = 0; h < 4; ++h) acc[h] += __shfl(e[h], ii) * p0[h * DH + lane];
      }
    }
#pragma unroll
    for (int h = 0; h < 4; ++h) acc[h] /= l[h];
  }
#pragma unroll
  for (int h = 0; h < 4; ++h) {
    float a = acc[h];
    bf16 hi = (bf16)a;
    aos[(size_t)bn * 512 + h * DH + lane] = hi;
    aos[(size_t)bn * 512 + 256 + h * DH + lane] = (bf16)(a - (float)hi);
  }
}

// ---------------------------------------------------------------------------
// epilogue: u = x + proj + bo; out = LN(u)*gamma + beta
// ---------------------------------------------------------------------------
__global__ __launch_bounds__(64) void ln_kernel(const float* __restrict__ x,
                                                const float* __restrict__ proj,
                                                const float* __restrict__ bo,
                                                const float* __restrict__ gamma,
                                                const float* __restrict__ beta,
                                                float* __restrict__ out) {
  int row = blockIdx.x;
  int lane = threadIdx.x;
  size_t base = (size_t)row * D + lane * 4;
  float4 xv = *(const float4*)(x + base);
  float4 pv = *(const float4*)(proj + base);
  float4 bv = *(const float4*)(bo + lane * 4);
  float u0 = xv.x + pv.x + bv.x, u1 = xv.y + pv.y + bv.y;
  float u2 = xv.z + pv.z + bv.z, u3 = xv.w + pv.w + bv.w;
  float s = u0 + u1 + u2 + u3;
  for (int off = 32; off; off >>= 1) s += __shfl_down(s, off);
  s = __shfl(s, 0);
  float mean = s * (1.0f / D);
  float d0 = u0 - mean, d1 = u1 - mean, d2 = u2 - mean, d3 = u3 - mean;
  float ss = d0 * d0 + d1 * d1 + d2 * d2 + d3 * d3;
  for (int off = 32; off; off >>= 1) ss += __shfl_down(ss, off);
  ss = __shfl(ss, 0);
  float rstd = rsqrtf(ss * (1.0f / D) + 1e-5f);
  float4 gv = *(const float4*)(gamma + lane * 4);
  float4 be = *(const float4*)(beta + lane * 4);
  float4 o;
  o.x = d0 * rstd * gv.x + be.x;
  o.y = d1 * rstd * gv.y + be.y;
  o.z = d2 * rstd * gv.z + be.z;
  o.w = d3 * rstd * gv.w + be.w;
  *(float4*)(out + base) = o;
}

// ---------------------------------------------------------------------------
// Workspace (83,132,416 B total — round-3-proven big layout):
//  phase A: XsN [0,12.58M) | sim [12.58M,79.69M) | mask | Wt
//  phase B (XsN+sim dead): XsRaw [0,8.39M) | qkv [8.39M,33.55M)
//                          aos [33.55M,41.94M) | proj [41.94M,50.33M)
// ---------------------------------------------------------------------------
extern "C" void kernel_launch(void* const* d_in, const int* in_sizes, int n_in,
                              void* d_out, int out_size, void* d_ws, size_t ws_size,
                              hipStream_t stream) {
  const float* x     = (const float*)d_in[0];
  const float* Wq    = (const float*)d_in[1];
  const float* Wk    = (const float*)d_in[2];
  const float* Wv    = (const float*)d_in[3];
  const float* Wo    = (const float*)d_in[4];
  const float* bo    = (const float*)d_in[5];
  const float* gamma = (const float*)d_in[6];
  const float* beta  = (const float*)d_in[7];
  float* out = (float*)d_out;

  char* ws = (char*)d_ws;
  bf16* XsN      = (bf16*)(ws);
  float* sim     = (float*)(ws + 12582912);
  unsigned* mask = (unsigned*)(ws + 79986688);
  bf16* Wt       = (bf16*)(ws + 82083840);
  bf16* XsRaw    = (bf16*)(ws);
  float* qkv     = (float*)(ws + 8388608);
  bf16* aos      = (bf16*)(ws + 33554432);
  float* proj    = (float*)(ws + 41943040);

  const int AMAP_SIM = PK6(0, 1, 0, 1, 0, 2);
  const int BMAP_SIM = PK6(0, 0, 1, 1, 2, 0);
  const int AMAP_2T  = PK3(0, 1, 0);
  const int BMAP_2T  = PK3(0, 0, 1);

  (void)hipMemsetAsync(mask, 0, (size_t)BATCH * N * (N / 32) * sizeof(unsigned), stream);
  prep_xn_w_kernel<<<9216, 64, 0, stream>>>(x, Wq, Wk, Wv, Wo, XsN, Wt);

  gemm_bt_kernel<<<dim3(544, 1, 1), 256, 0, stream>>>(
      XsN, XsN, sim, 768, 768, N, 48, AMAP_SIM, BMAP_SIM,
      (long)N * 768, (long)N * 768, (long)N * N, 1);
  topk_adj_kernel<<<BATCH * N, 64, 0, stream>>>(sim, mask);

  prep_raw_kernel<<<BATCH * N, 64, 0, stream>>>(x, XsRaw);
  gemm_bt_kernel<<<dim3(6, 64, 1), 256, 0, stream>>>(
      XsRaw, Wt, qkv, 512, 512, 768, 16, AMAP_2T, BMAP_2T, 0, 0, 0, 0);

  attn_kernel<<<(BATCH * N) / 4, 256, 0, stream>>>(qkv, mask, aos);

  gemm_bt_kernel<<<dim3(2, 64, 1), 256, 0, stream>>>(
      aos, Wt + (size_t)768 * 512, proj, 512, 512, D, 16, AMAP_2T, BMAP_2T, 0, 0, 0, 0);
  ln_kernel<<<BATCH * N, 64, 0, stream>>>(x, proj, bo, gamma, beta, out);
}

// Round 11
// 230.461 us; speedup vs baseline: 1.0103x; 1.0056x over previous
//
#include <hip/hip_runtime.h>
#include <hip/hip_bf16.h>
#include <math.h>

#define BATCH 4
#define N 2048
#define D 256
#define NH 4
#define DH 64
#define TOPK 9
#define NEG_BIG -1e30f

typedef __bf16 bf16;
typedef __bf16 bf16x8 __attribute__((ext_vector_type(8)));
typedef float f32x4 __attribute__((ext_vector_type(4)));

#define PK3(a,b,c) ((a) | ((b) << 2) | ((c) << 4))
#define PK6(a,b,c,d,e,f) ((a) | ((b) << 2) | ((c) << 4) | ((d) << 6) | ((e) << 8) | ((f) << 10))

// s_waitcnt with ONLY vmcnt=N (lgkmcnt=15/expcnt=7 = no wait). gfx9 encoding:
// vmcnt[3:0]@0, expcnt@4, lgkmcnt@8, vmcnt[5:4]@14.
#define WAITVM(Nc) __builtin_amdgcn_s_waitcnt((((Nc) & 0xf)) | (7u << 4) | (0xfu << 8) | ((((unsigned)(Nc)) >> 4) << 14))

__device__ __forceinline__ void async_cp16(const bf16* g, const bf16* l) {
  __builtin_amdgcn_global_load_lds(
      (const __attribute__((address_space(1))) void*)(uintptr_t)g,
      (__attribute__((address_space(3))) void*)(uintptr_t)l, 16, 0, 0);
}

// ---------------------------------------------------------------------------
// prep: blk<8192: x -> XsN (L2-norm, 3-way split, stride 768)
//       blk>=8192: W{q,k,v,o} -> Wt (transpose + 2-way split)
// ---------------------------------------------------------------------------
__global__ __launch_bounds__(64) void prep_xn_w_kernel(const float* __restrict__ x,
                                                       const float* __restrict__ Wq,
                                                       const float* __restrict__ Wk,
                                                       const float* __restrict__ Wv,
                                                       const float* __restrict__ Wo,
                                                       bf16* __restrict__ XsN,
                                                       bf16* __restrict__ Wt) {
  int blk = blockIdx.x;
  int lane = threadIdx.x;
  if (blk < 8192) {
    float4 v = *(const float4*)(x + (size_t)blk * D + lane * 4);
    float ss = v.x * v.x + v.y * v.y + v.z * v.z + v.w * v.w;
    for (int off = 32; off; off >>= 1) ss += __shfl_down(ss, off);
    ss = __shfl(ss, 0);
    float sc = 1.0f / fmaxf(sqrtf(ss), 1e-12f);
    float xs[4] = {v.x * sc, v.y * sc, v.z * sc, v.w * sc};
    bf16* o = XsN + (size_t)blk * 768 + lane * 4;
#pragma unroll
    for (int j = 0; j < 4; ++j) {
      float xv = xs[j];
      bf16 h = (bf16)xv;
      float r1 = xv - (float)h;
      bf16 m = (bf16)r1;
      o[j] = h;
      o[256 + j] = m;
      o[512 + j] = (bf16)(r1 - (float)m);
    }
  } else {
    int jj = blk - 8192;
    const float* W = (jj < 256) ? Wq : (jj < 512) ? Wk : (jj < 768) ? Wv : Wo;
    int j = jj & 255;
    bf16* dst = Wt + (size_t)jj * 512;
    for (int k = lane; k < 256; k += 64) {
      float w = W[(size_t)k * D + j];
      bf16 h = (bf16)w;
      dst[k] = h;
      dst[256 + k] = (bf16)(w - (float)h);
    }
  }
}

// prep phase 2: x -> XsRaw (2-way split, stride 512) — runs after sim is dead
__global__ __launch_bounds__(64) void prep_raw_kernel(const float* __restrict__ x,
                                                      bf16* __restrict__ XsRaw) {
  int row = blockIdx.x;
  int lane = threadIdx.x;
  float4 v = *(const float4*)(x + (size_t)row * D + lane * 4);
  float xs[4] = {v.x, v.y, v.z, v.w};
  bf16* o = XsRaw + (size_t)row * 512 + lane * 4;
#pragma unroll
  for (int j = 0; j < 4; ++j) {
    bf16 h = (bf16)xs[j];
    o[j] = h;
    o[256 + j] = (bf16)(xs[j] - (float)h);
  }
}

// ---------------------------------------------------------------------------
// MFMA GEMM, BK=32, THREE LDS buffers, prefetch depth 2 (issue st+2, then
// WAITVM(8): 12 outstanding - 8 => step st's 4 loads retired).  48 KB LDS
// -> 3 blocks/CU -> all 544 sim blocks co-resident (no dispatch tail), and
// each load gets ~2 steps of slack (covers L2 ~200 cyc).  Swizzle key
// (row>>1)&3 (2-way = free, m136; verified 0 conflicts in round 10).
// mode 0: generic C = A@B^T, grid (Nc/128, M/128, batches).
// mode 1: symmetric sim = A@A^T, grid (544,1,1), XCD-aware triangular decode;
//         nontemporal C stores (incl. mirror).
// ---------------------------------------------------------------------------
__global__ __launch_bounds__(256) void gemm_bt_kernel(const bf16* __restrict__ A,
                                                      const bf16* __restrict__ B,
                                                      float* __restrict__ C,
                                                      int lda, int ldb, int ldc,
                                                      int nsteps, int amap, int bmap,
                                                      long sA, long sB, long sC,
                                                      int mode) {
  __shared__ bf16 As[3][128 * 32];
  __shared__ bf16 Bs[3][128 * 32];
  int tid = threadIdx.x;
  int lane = tid & 63;
  int wv = tid >> 6;
  int wm = (wv >> 1) * 64;
  int wn = (wv & 1) * 64;
  int bx, by, z;
  if (mode) {  // XCD-aware triangular decode
    int g = blockIdx.x;
    int xcd = g & 7;
    int slot = g >> 3;          // 0..67
    z = xcd >> 1;
    int t = (xcd & 1) * 68 + slot;  // pair 0..135
    by = 0;
    while (t >= 16 - by) { t -= 16 - by; ++by; }
    bx = by + t;
  } else {
    bx = blockIdx.x;
    by = blockIdx.y;
    z = blockIdx.z;
  }
  int row0 = by * 128;
  int col0 = bx * 128;
  const bf16* Ab = A + (size_t)z * sA + (size_t)row0 * lda;
  const bf16* Bb = B + (size_t)z * sB + (size_t)col0 * ldb;
  float* Cb = C + (size_t)z * sC;

  // staging: instr q in 0..1 per matrix; slot = q*256+tid covers
  // row = q*64 + (tid>>2), physical granule c = tid&3; fetch source granule
  // c ^ ((row>>1)&3)  (q*64 drops out mod 4).
  int rth = tid >> 2;                  // 0..63
  int gperm = (tid & 3) ^ ((rth >> 1) & 3);
  const bf16* ga0 = Ab + (size_t)rth * lda + gperm * 8;
  const bf16* gb0 = Bb + (size_t)rth * ldb + gperm * 8;
  int ldsoff = tid * 8;  // 16 B per thread per instr

  int fr = lane & 15;
  int G = lane >> 4;       // logical granule 0..3 (k-offset = G*8)

  f32x4 acc[4][4] = {};

  auto issue = [&](int st, int buf) {
    int ch = st >> 3;
    int aoff = (((amap >> (ch * 2)) & 3) << 8) | ((st & 7) << 5);
    int boff = (((bmap >> (ch * 2)) & 3) << 8) | ((st & 7) << 5);
#pragma unroll
    for (int q = 0; q < 2; ++q)
      async_cp16(ga0 + (size_t)q * 64 * lda + aoff, &As[buf][ldsoff + q * 2048]);
#pragma unroll
    for (int q = 0; q < 2; ++q)
      async_cp16(gb0 + (size_t)q * 64 * ldb + boff, &Bs[buf][ldsoff + q * 2048]);
  };

  issue(0, 0);
  issue(1, 1);
  int pbuf = 2;  // prefetch target (st+2)
  int cbuf = 0;  // compute buffer (st)
  for (int st = 0; st < nsteps; ++st) {
    if (st + 2 < nsteps) {
      issue(st + 2, pbuf);
      WAITVM(8);   // 12 outstanding -> wait to <=8: step st's 4 loads retired
    } else {
      WAITVM(0);
    }
    __builtin_amdgcn_s_barrier();  // all waves' staging for cbuf visible
    bf16x8 af[4], bfr[4];
#pragma unroll
    for (int mi = 0; mi < 4; ++mi) {
      int r = wm + mi * 16 + fr;
      af[mi] = *(const bf16x8*)&As[cbuf][r * 32 + ((G ^ ((r >> 1) & 3)) << 3)];
    }
#pragma unroll
    for (int nj = 0; nj < 4; ++nj) {
      int r = wn + nj * 16 + fr;
      bfr[nj] = *(const bf16x8*)&Bs[cbuf][r * 32 + ((G ^ ((r >> 1) & 3)) << 3)];
    }
#pragma unroll
    for (int mi = 0; mi < 4; ++mi)
#pragma unroll
      for (int nj = 0; nj < 4; ++nj)
        acc[mi][nj] = __builtin_amdgcn_mfma_f32_16x16x32_bf16(af[mi], bfr[nj], acc[mi][nj], 0, 0, 0);
    __builtin_amdgcn_s_barrier();  // reads of cbuf done; it becomes next pbuf
    pbuf = cbuf;
    cbuf = (cbuf == 2) ? 0 : cbuf + 1;
  }

  int er = (lane >> 4) * 4;
  int ec = lane & 15;
#pragma unroll
  for (int mi = 0; mi < 4; ++mi)
#pragma unroll
    for (int nj = 0; nj < 4; ++nj) {
      int rb = row0 + wm + mi * 16 + er;
      int cb = col0 + wn + nj * 16 + ec;
      if (mode) {
#pragma unroll
        for (int reg = 0; reg < 4; ++reg)
          __builtin_nontemporal_store(acc[mi][nj][reg],
                                      &Cb[(size_t)(rb + reg) * ldc + cb]);
        if (bx != by) {
#pragma unroll
          for (int reg = 0; reg < 4; ++reg)
            __builtin_nontemporal_store(acc[mi][nj][reg],
                                        &Cb[(size_t)cb * ldc + rb + reg]);
        }
      } else {
#pragma unroll
        for (int reg = 0; reg < 4; ++reg)
          Cb[(size_t)(rb + reg) * ldc + cb] = acc[mi][nj][reg];
      }
    }
}

// ---------------------------------------------------------------------------
// top-9 per row by 9x extract-max (branch-free masked argmax in registers),
// fused adjacency write. One wave per row; mask pre-zeroed.
// Selection set identical to lax.top_k: (value desc, index asc) tie-break.
// ---------------------------------------------------------------------------
__global__ __launch_bounds__(64) void topk_adj_kernel(const float* __restrict__ sim,
                                                      unsigned* __restrict__ mask) {
  int row = blockIdx.x;
  int lane = threadIdx.x;
  int b = row >> 11, r = row & 2047;
  const float* srow = sim + (size_t)row * N;
  float v[32];
#pragma unroll
  for (int it = 0; it < 8; ++it) {
    float4 q = *(const float4*)(srow + it * 256 + lane * 4);
    v[it * 4 + 0] = q.x; v[it * 4 + 1] = q.y;
    v[it * 4 + 2] = q.z; v[it * 4 + 3] = q.w;
  }
  unsigned removed = 0;
  for (int rs = 0; rs < TOPK; ++rs) {
    float m = -3e38f;
    int mi = 0;
#pragma unroll
    for (int i = 0; i < 32; ++i) {
      float vv = ((removed >> i) & 1u) ? -3e38f : v[i];
      if (vv > m) { m = vv; mi = i; }  // ascending i = ascending global idx
    }
    int gidx = ((mi >> 2) << 8) + lane * 4 + (mi & 3);
    for (int off = 32; off; off >>= 1) {
      float om = __shfl_down(m, off);
      int og = __shfl_down(gidx, off);
      if (om > m || (om == m && og < gidx)) { m = om; gidx = og; }
    }
    gidx = __shfl(gidx, 0);
    if (((gidx >> 2) & 63) == lane)
      removed |= 1u << (((gidx >> 8) << 2) | (gidx & 3));
    if (lane == 0) {
      atomicOr(&mask[(size_t)row * 64 + (gidx >> 5)], 1u << (gidx & 31));
      atomicOr(&mask[(((size_t)b << 11) + gidx) * 64 + (r >> 5)], 1u << (r & 31));
    }
  }
}

// ---------------------------------------------------------------------------
// sparse attention: 4 waves/block, one (b,n) row per wave; writes bf16-split
// aos (stride 512) directly.
// ---------------------------------------------------------------------------
__global__ __launch_bounds__(256) void attn_kernel(const float* __restrict__ qkv,
                                                   const unsigned* __restrict__ mask,
                                                   bf16* __restrict__ aos) {
  __shared__ float sq[4][256];
  __shared__ unsigned short nbr[4][2048];
  __shared__ int s_nn[4];
  int wv = threadIdx.x >> 6;
  int lane = threadIdx.x & 63;
  int bn = blockIdx.x * 4 + wv;
  int b = bn >> 11;
  if (lane == 0) s_nn[wv] = 0;
  *(float4*)&sq[wv][lane * 4] = *(const float4*)(qkv + (size_t)bn * 768 + lane * 4);
  __syncthreads();
  unsigned bits = mask[(size_t)bn * (N / 32) + lane];
  while (bits) {
    int bit = __ffs(bits) - 1;
    bits &= bits - 1;
    int p = atomicAdd(&s_nn[wv], 1);
    nbr[wv][p] = (unsigned short)(lane * 32 + bit);
  }
  __syncthreads();
  int nn = s_nn[wv];
  const float* base = qkv + (size_t)b * N * 768;
  float acc[4] = {0.f, 0.f, 0.f, 0.f};

  auto score4 = [&](int j, float* s) {
    const float* kr = base + (size_t)j * 768 + 256;
#pragma unroll
    for (int h = 0; h < 4; ++h) {
      float a = 0.f;
#pragma unroll
      for (int c = 0; c < DH; c += 4) {
        float4 kk = *(const float4*)(kr + h * DH + c);
        a += sq[wv][h * DH + c] * kk.x + sq[wv][h * DH + c + 1] * kk.y +
             sq[wv][h * DH + c + 2] * kk.z + sq[wv][h * DH + c + 3] * kk.w;
      }
      s[h] = a * 0.125f;
    }
  };

  if (nn <= 64) {
    float s[4] = {NEG_BIG, NEG_BIG, NEG_BIG, NEG_BIG};
    if (lane < nn) score4(nbr[wv][lane], s);
    float w[4], l[4];
#pragma unroll
    for (int h = 0; h < 4; ++h) {
      float m = s[h];
      for (int off = 32; off; off >>= 1) m = fmaxf(m, __shfl_down(m, off));
      m = __shfl(m, 0);
      float e = (lane < nn) ? __expf(s[h] - m) : 0.f;
      float ls = e;
      for (int off = 32; off; off >>= 1) ls += __shfl_down(ls, off);
      l[h] = __shfl(ls, 0);
      w[h] = e;
    }
    int i = 0;
    for (; i + 4 <= nn; i += 4) {
      int j0 = nbr[wv][i + 0], j1 = nbr[wv][i + 1];
      int j2 = nbr[wv][i + 2], j3 = nbr[wv][i + 3];
      const float* p0 = base + (size_t)j0 * 768 + 512;
      const float* p1 = base + (size_t)j1 * 768 + 512;
      const float* p2 = base + (size_t)j2 * 768 + 512;
      const float* p3 = base + (size_t)j3 * 768 + 512;
#pragma unroll
      for (int h = 0; h < 4; ++h) {
        acc[h] += __shfl(w[h], i + 0) * p0[h * DH + lane] +
                  __shfl(w[h], i + 1) * p1[h * DH + lane] +
                  __shfl(w[h], i + 2) * p2[h * DH + lane] +
                  __shfl(w[h], i + 3) * p3[h * DH + lane];
      }
    }
    for (; i < nn; ++i) {
      const float* p0 = base + (size_t)nbr[wv][i] * 768 + 512;
#pragma unroll
      for (int h = 0; h < 4; ++h) acc[h] += __shfl(w[h], i) * p0[h * DH + lane];
    }
#pragma unroll
    for (int h = 0; h < 4; ++h) acc[h] /= l[h];
  } else {
    float m[4] = {NEG_BIG, NEG_BIG, NEG_BIG, NEG_BIG};
    for (int i0 = 0; i0 < nn; i0 += 64) {
      float s[4] = {NEG_BIG, NEG_BIG, NEG_BIG, NEG_BIG};
      if (i0 + lane < nn) score4(nbr[wv][i0 + lane], s);
#pragma unroll
      for (int h = 0; h < 4; ++h) m[h] = fmaxf(m[h], s[h]);
    }
#pragma unroll
    for (int h = 0; h < 4; ++h) {
      for (int off = 32; off; off >>= 1) m[h] = fmaxf(m[h], __shfl_down(m[h], off));
      m[h] = __shfl(m[h], 0);
    }
    float l[4] = {0.f, 0.f, 0.f, 0.f};
    for (int i0 = 0; i0 < nn; i0 += 64) {
      float s[4] = {NEG_BIG, NEG_BIG, NEG_BIG, NEG_BIG};
      if (i0 + lane < nn) score4(nbr[wv][i0 + lane], s);
      float e[4];
#pragma unroll
      for (int h = 0; h < 4; ++h) {
        e[h] = (i0 + lane < nn) ? __expf(s[h] - m[h]) : 0.f;
        float ls = e[h];
        for (int off = 32; off; off >>= 1) ls += __shfl_down(ls, off);
        l[h] += __shfl(ls, 0);
      }
      int lim = min(64, nn - i0);
      for (int ii = 0; ii < lim; ++ii) {
        const float* p0 = base + (size_t)nbr[wv][i0 + ii] * 768 + 512;
#pragma unroll
        for (int h = 0; h < 4; ++h) acc[h] += __shfl(e[h], ii) * p0[h * DH + lane];
      }
    }
#pragma unroll
    for (int h = 0; h < 4; ++h) acc[h] /= l[h];
  }
#pragma unroll
  for (int h = 0; h < 4; ++h) {
    float a = acc[h];
    bf16 hi = (bf16)a;
    aos[(size_t)bn * 512 + h * DH + lane] = hi;
    aos[(size_t)bn * 512 + 256 + h * DH + lane] = (bf16)(a - (float)hi);
  }
}

// ---------------------------------------------------------------------------
// epilogue: u = x + proj + bo; out = LN(u)*gamma + beta
// ---------------------------------------------------------------------------
__global__ __launch_bounds__(64) void ln_kernel(const float* __restrict__ x,
                                                const float* __restrict__ proj,
                                                const float* __restrict__ bo,
                                                const float* __restrict__ gamma,
                                                const float* __restrict__ beta,
                                                float* __restrict__ out) {
  int row = blockIdx.x;
  int lane = threadIdx.x;
  size_t base = (size_t)row * D + lane * 4;
  float4 xv = *(const float4*)(x + base);
  float4 pv = *(const float4*)(proj + base);
  float4 bv = *(const float4*)(bo + lane * 4);
  float u0 = xv.x + pv.x + bv.x, u1 = xv.y + pv.y + bv.y;
  float u2 = xv.z + pv.z + bv.z, u3 = xv.w + pv.w + bv.w;
  float s = u0 + u1 + u2 + u3;
  for (int off = 32; off; off >>= 1) s += __shfl_down(s, off);
  s = __shfl(s, 0);
  float mean = s * (1.0f / D);
  float d0 = u0 - mean, d1 = u1 - mean, d2 = u2 - mean, d3 = u3 - mean;
  float ss = d0 * d0 + d1 * d1 + d2 * d2 + d3 * d3;
  for (int off = 32; off; off >>= 1) ss += __shfl_down(ss, off);
  ss = __shfl(ss, 0);
  float rstd = rsqrtf(ss * (1.0f / D) + 1e-5f);
  float4 gv = *(const float4*)(gamma + lane * 4);
  float4 be = *(const float4*)(beta + lane * 4);
  float4 o;
  o.x = d0 * rstd * gv.x + be.x;
  o.y = d1 * rstd * gv.y + be.y;
  o.z = d2 * rstd * gv.z + be.z;
  o.w = d3 * rstd * gv.w + be.w;
  *(float4*)(out + base) = o;
}

// ---------------------------------------------------------------------------
// Workspace (83,132,416 B total — round-3-proven big layout):
//  phase A: XsN [0,12.58M) | sim [12.58M,79.69M) | mask | Wt
//  phase B (XsN+sim dead): XsRaw [0,8.39M) | qkv [8.39M,33.55M)
//                          aos [33.55M,41.94M) | proj [41.94M,50.33M)
// ---------------------------------------------------------------------------
extern "C" void kernel_launch(void* const* d_in, const int* in_sizes, int n_in,
                              void* d_out, int out_size, void* d_ws, size_t ws_size,
                              hipStream_t stream) {
  const float* x     = (const float*)d_in[0];
  const float* Wq    = (const float*)d_in[1];
  const float* Wk    = (const float*)d_in[2];
  const float* Wv    = (const float*)d_in[3];
  const float* Wo    = (const float*)d_in[4];
  const float* bo    = (const float*)d_in[5];
  const float* gamma = (const float*)d_in[6];
  const float* beta  = (const float*)d_in[7];
  float* out = (float*)d_out;

  char* ws = (char*)d_ws;
  bf16* XsN      = (bf16*)(ws);
  float* sim     = (float*)(ws + 12582912);
  unsigned* mask = (unsigned*)(ws + 79986688);
  bf16* Wt       = (bf16*)(ws + 82083840);
  bf16* XsRaw    = (bf16*)(ws);
  float* qkv     = (float*)(ws + 8388608);
  bf16* aos      = (bf16*)(ws + 33554432);
  float* proj    = (float*)(ws + 41943040);

  const int AMAP_SIM = PK6(0, 1, 0, 1, 0, 2);
  const int BMAP_SIM = PK6(0, 0, 1, 1, 2, 0);
  const int AMAP_2T  = PK3(0, 1, 0);
  const int BMAP_2T  = PK3(0, 0, 1);

  (void)hipMemsetAsync(mask, 0, (size_t)BATCH * N * (N / 32) * sizeof(unsigned), stream);
  prep_xn_w_kernel<<<9216, 64, 0, stream>>>(x, Wq, Wk, Wv, Wo, XsN, Wt);

  gemm_bt_kernel<<<dim3(544, 1, 1), 256, 0, stream>>>(
      XsN, XsN, sim, 768, 768, N, 48, AMAP_SIM, BMAP_SIM,
      (long)N * 768, (long)N * 768, (long)N * N, 1);
  topk_adj_kernel<<<BATCH * N, 64, 0, stream>>>(sim, mask);

  prep_raw_kernel<<<BATCH * N, 64, 0, stream>>>(x, XsRaw);
  gemm_bt_kernel<<<dim3(6, 64, 1), 256, 0, stream>>>(
      XsRaw, Wt, qkv, 512, 512, 768, 16, AMAP_2T, BMAP_2T, 0, 0, 0, 0);

  attn_kernel<<<(BATCH * N) / 4, 256, 0, stream>>>(qkv, mask, aos);

  gemm_bt_kernel<<<dim3(2, 64, 1), 256, 0, stream>>>(
      aos, Wt + (size_t)768 * 512, proj, 512, 512, D, 16, AMAP_2T, BMAP_2T, 0, 0, 0, 0);
  ln_kernel<<<BATCH * N, 64, 0, stream>>>(x, proj, bo, gamma, beta, out);
}

// Round 12
// 218.680 us; speedup vs baseline: 1.0648x; 1.0539x over previous
//
#include <hip/hip_runtime.h>
#include <hip/hip_bf16.h>
#include <math.h>

#define BATCH 4
#define N 2048
#define D 256
#define NH 4
#define DH 64
#define TOPK 9
#define NEG_BIG -1e30f

typedef __bf16 bf16;
typedef __bf16 bf16x8 __attribute__((ext_vector_type(8)));
typedef float f32x4 __attribute__((ext_vector_type(4)));

#define PK3(a,b,c) ((a) | ((b) << 2) | ((c) << 4))
#define PK6(a,b,c,d,e,f) ((a) | ((b) << 2) | ((c) << 4) | ((d) << 6) | ((e) << 8) | ((f) << 10))

// s_waitcnt with ONLY vmcnt=N (lgkmcnt=15/expcnt=7 = no wait). gfx9 encoding:
// vmcnt[3:0]@0, expcnt@4, lgkmcnt@8, vmcnt[5:4]@14.
#define WAITVM(Nc) __builtin_amdgcn_s_waitcnt((((Nc) & 0xf)) | (7u << 4) | (0xfu << 8) | ((((unsigned)(Nc)) >> 4) << 14))

__device__ __forceinline__ void async_cp16(const bf16* g, const bf16* l) {
  __builtin_amdgcn_global_load_lds(
      (const __attribute__((address_space(1))) void*)(uintptr_t)g,
      (__attribute__((address_space(3))) void*)(uintptr_t)l, 16, 0, 0);
}

// ---------------------------------------------------------------------------
// prep: blk<8192: x -> XsN (L2-norm, 3-way split, stride 768)
//       blk>=8192: W{q,k,v,o} -> Wt (transpose + 2-way split)
// ---------------------------------------------------------------------------
__global__ __launch_bounds__(64) void prep_xn_w_kernel(const float* __restrict__ x,
                                                       const float* __restrict__ Wq,
                                                       const float* __restrict__ Wk,
                                                       const float* __restrict__ Wv,
                                                       const float* __restrict__ Wo,
                                                       bf16* __restrict__ XsN,
                                                       bf16* __restrict__ Wt) {
  int blk = blockIdx.x;
  int lane = threadIdx.x;
  if (blk < 8192) {
    float4 v = *(const float4*)(x + (size_t)blk * D + lane * 4);
    float ss = v.x * v.x + v.y * v.y + v.z * v.z + v.w * v.w;
    for (int off = 32; off; off >>= 1) ss += __shfl_down(ss, off);
    ss = __shfl(ss, 0);
    float sc = 1.0f / fmaxf(sqrtf(ss), 1e-12f);
    float xs[4] = {v.x * sc, v.y * sc, v.z * sc, v.w * sc};
    bf16* o = XsN + (size_t)blk * 768 + lane * 4;
#pragma unroll
    for (int j = 0; j < 4; ++j) {
      float xv = xs[j];
      bf16 h = (bf16)xv;
      float r1 = xv - (float)h;
      bf16 m = (bf16)r1;
      o[j] = h;
      o[256 + j] = m;
      o[512 + j] = (bf16)(r1 - (float)m);
    }
  } else {
    int jj = blk - 8192;
    const float* W = (jj < 256) ? Wq : (jj < 512) ? Wk : (jj < 768) ? Wv : Wo;
    int j = jj & 255;
    bf16* dst = Wt + (size_t)jj * 512;
    for (int k = lane; k < 256; k += 64) {
      float w = W[(size_t)k * D + j];
      bf16 h = (bf16)w;
      dst[k] = h;
      dst[256 + k] = (bf16)(w - (float)h);
    }
  }
}

// prep phase 2: x -> XsRaw (2-way split, stride 512) — runs after sim is dead
__global__ __launch_bounds__(64) void prep_raw_kernel(const float* __restrict__ x,
                                                      bf16* __restrict__ XsRaw) {
  int row = blockIdx.x;
  int lane = threadIdx.x;
  float4 v = *(const float4*)(x + (size_t)row * D + lane * 4);
  float xs[4] = {v.x, v.y, v.z, v.w};
  bf16* o = XsRaw + (size_t)row * 512 + lane * 4;
#pragma unroll
  for (int j = 0; j < 4; ++j) {
    bf16 h = (bf16)xs[j];
    o[j] = h;
    o[256 + j] = (bf16)(xs[j] - (float)h);
  }
}

// ---------------------------------------------------------------------------
// MFMA GEMM — round-8 proven structure: BK=64, LDS double-buffer (64 KB,
// 2 blocks/CU), global_load_lds staging, raw s_barrier + vmcnt(8), XOR
// swizzle key (row&7) (verified 0 conflicts, rounds 7-8).
// mode 0: generic C = A@B^T, grid (Nc/128, M/128, batches).
// mode 1: symmetric sim = A@A^T, grid (544,1,1), XCD-aware triangular decode
//         (FETCH 124->14 MB, round 8); nontemporal C stores (incl. mirror).
// ---------------------------------------------------------------------------
__global__ __launch_bounds__(256) void gemm_bt_kernel(const bf16* __restrict__ A,
                                                      const bf16* __restrict__ B,
                                                      float* __restrict__ C,
                                                      int lda, int ldb, int ldc,
                                                      int nsteps, int amap, int bmap,
                                                      long sA, long sB, long sC,
                                                      int mode) {
  __shared__ bf16 As[2][128 * 64];
  __shared__ bf16 Bs[2][128 * 64];
  int tid = threadIdx.x;
  int lane = tid & 63;
  int wv = tid >> 6;
  int wm = (wv >> 1) * 64;
  int wn = (wv & 1) * 64;
  int bx, by, z;
  if (mode) {  // XCD-aware triangular decode
    int g = blockIdx.x;
    int xcd = g & 7;
    int slot = g >> 3;          // 0..67
    z = xcd >> 1;
    int t = (xcd & 1) * 68 + slot;  // pair 0..135
    by = 0;
    while (t >= 16 - by) { t -= 16 - by; ++by; }
    bx = by + t;
  } else {
    bx = blockIdx.x;
    by = blockIdx.y;
    z = blockIdx.z;
  }
  int row0 = by * 128;
  int col0 = bx * 128;
  const bf16* Ab = A + (size_t)z * sA + (size_t)row0 * lda;
  const bf16* Bb = B + (size_t)z * sB + (size_t)col0 * ldb;
  float* Cb = C + (size_t)z * sC;

  int rbase = tid >> 3;
  int gperm = (tid & 7) ^ (rbase & 7);
  const bf16* ga0 = Ab + (size_t)rbase * lda + gperm * 8;
  const bf16* gb0 = Bb + (size_t)rbase * ldb + gperm * 8;
  int ldsoff = tid * 8;  // 16 B per thread

  int fr = lane & 15;
  int fq = (lane >> 4) * 8;

  f32x4 acc[4][4] = {};

  auto issue = [&](int st, int buf) {
    int ch = st >> 2;
    int aoff = (((amap >> (ch * 2)) & 3) << 8) | ((st & 3) << 6);
    int boff = (((bmap >> (ch * 2)) & 3) << 8) | ((st & 3) << 6);
#pragma unroll
    for (int q = 0; q < 4; ++q)
      async_cp16(ga0 + (size_t)q * 32 * lda + aoff, &As[buf][ldsoff + q * 2048]);
#pragma unroll
    for (int q = 0; q < 4; ++q)
      async_cp16(gb0 + (size_t)q * 32 * ldb + boff, &Bs[buf][ldsoff + q * 2048]);
  };

  issue(0, 0);
  for (int st = 0; st < nsteps; ++st) {
    int buf = st & 1;
    if (st + 1 < nsteps) {
      issue(st + 1, buf ^ 1);
      WAITVM(8);   // in-order retire: <=8 outstanding => buf st fully landed
    } else {
      WAITVM(0);
    }
    __builtin_amdgcn_s_barrier();  // all waves' staging for buf visible
#pragma unroll
    for (int ks = 0; ks < 64; ks += 32) {
      bf16x8 af[4], bfr[4];
#pragma unroll
      for (int mi = 0; mi < 4; ++mi) {
        int r = wm + mi * 16 + fr;
        int G = (ks + fq) >> 3;
        af[mi] = *(const bf16x8*)&As[buf][r * 64 + ((G ^ (r & 7)) << 3)];
      }
#pragma unroll
      for (int nj = 0; nj < 4; ++nj) {
        int r = wn + nj * 16 + fr;
        int G = (ks + fq) >> 3;
        bfr[nj] = *(const bf16x8*)&Bs[buf][r * 64 + ((G ^ (r & 7)) << 3)];
      }
#pragma unroll
      for (int mi = 0; mi < 4; ++mi)
#pragma unroll
        for (int nj = 0; nj < 4; ++nj)
          acc[mi][nj] = __builtin_amdgcn_mfma_f32_16x16x32_bf16(af[mi], bfr[nj], acc[mi][nj], 0, 0, 0);
    }
    __builtin_amdgcn_s_barrier();  // reads of buf done before st+2 overwrites it
  }

  int er = (lane >> 4) * 4;
  int ec = lane & 15;
#pragma unroll
  for (int mi = 0; mi < 4; ++mi)
#pragma unroll
    for (int nj = 0; nj < 4; ++nj) {
      int rb = row0 + wm + mi * 16 + er;
      int cb = col0 + wn + nj * 16 + ec;
      if (mode) {
#pragma unroll
        for (int reg = 0; reg < 4; ++reg)
          __builtin_nontemporal_store(acc[mi][nj][reg],
                                      &Cb[(size_t)(rb + reg) * ldc + cb]);
        if (bx != by) {
#pragma unroll
          for (int reg = 0; reg < 4; ++reg)
            __builtin_nontemporal_store(acc[mi][nj][reg],
                                        &Cb[(size_t)cb * ldc + rb + reg]);
        }
      } else {
#pragma unroll
        for (int reg = 0; reg < 4; ++reg)
          Cb[(size_t)(rb + reg) * ldc + cb] = acc[mi][nj][reg];
      }
    }
}

// ---------------------------------------------------------------------------
// top-9 per row by 9x extract-max (branch-free masked argmax in registers),
// fused adjacency write. One wave per row; mask pre-zeroed.
// Selection set identical to lax.top_k: (value desc, index asc) tie-break.
// ---------------------------------------------------------------------------
__global__ __launch_bounds__(64) void topk_adj_kernel(const float* __restrict__ sim,
                                                      unsigned* __restrict__ mask) {
  int row = blockIdx.x;
  int lane = threadIdx.x;
  int b = row >> 11, r = row & 2047;
  const float* srow = sim + (size_t)row * N;
  float v[32];
#pragma unroll
  for (int it = 0; it < 8; ++it) {
    float4 q = *(const float4*)(srow + it * 256 + lane * 4);
    v[it * 4 + 0] = q.x; v[it * 4 + 1] = q.y;
    v[it * 4 + 2] = q.z; v[it * 4 + 3] = q.w;
  }
  unsigned removed = 0;
  for (int rs = 0; rs < TOPK; ++rs) {
    float m = -3e38f;
    int mi = 0;
#pragma unroll
    for (int i = 0; i < 32; ++i) {
      float vv = ((removed >> i) & 1u) ? -3e38f : v[i];
      if (vv > m) { m = vv; mi = i; }  // ascending i = ascending global idx
    }
    int gidx = ((mi >> 2) << 8) + lane * 4 + (mi & 3);
    for (int off = 32; off; off >>= 1) {
      float om = __shfl_down(m, off);
      int og = __shfl_down(gidx, off);
      if (om > m || (om == m && og < gidx)) { m = om; gidx = og; }
    }
    gidx = __shfl(gidx, 0);
    if (((gidx >> 2) & 63) == lane)
      removed |= 1u << (((gidx >> 8) << 2) | (gidx & 3));
    if (lane == 0) {
      atomicOr(&mask[(size_t)row * 64 + (gidx >> 5)], 1u << (gidx & 31));
      atomicOr(&mask[(((size_t)b << 11) + gidx) * 64 + (r >> 5)], 1u << (r & 31));
    }
  }
}

// ---------------------------------------------------------------------------
// sparse attention: 4 waves/block, one (b,n) row per wave; writes bf16-split
// aos (stride 512) directly.
// ---------------------------------------------------------------------------
__global__ __launch_bounds__(256) void attn_kernel(const float* __restrict__ qkv,
                                                   const unsigned* __restrict__ mask,
                                                   bf16* __restrict__ aos) {
  __shared__ float sq[4][256];
  __shared__ unsigned short nbr[4][2048];
  __shared__ int s_nn[4];
  int wv = threadIdx.x >> 6;
  int lane = threadIdx.x & 63;
  int bn = blockIdx.x * 4 + wv;
  int b = bn >> 11;
  if (lane == 0) s_nn[wv] = 0;
  *(float4*)&sq[wv][lane * 4] = *(const float4*)(qkv + (size_t)bn * 768 + lane * 4);
  __syncthreads();
  unsigned bits = mask[(size_t)bn * (N / 32) + lane];
  while (bits) {
    int bit = __ffs(bits) - 1;
    bits &= bits - 1;
    int p = atomicAdd(&s_nn[wv], 1);
    nbr[wv][p] = (unsigned short)(lane * 32 + bit);
  }
  __syncthreads();
  int nn = s_nn[wv];
  const float* base = qkv + (size_t)b * N * 768;
  float acc[4] = {0.f, 0.f, 0.f, 0.f};

  auto score4 = [&](int j, float* s) {
    const float* kr = base + (size_t)j * 768 + 256;
#pragma unroll
    for (int h = 0; h < 4; ++h) {
      float a = 0.f;
#pragma unroll
      for (int c = 0; c < DH; c += 4) {
        float4 kk = *(const float4*)(kr + h * DH + c);
        a += sq[wv][h * DH + c] * kk.x + sq[wv][h * DH + c + 1] * kk.y +
             sq[wv][h * DH + c + 2] * kk.z + sq[wv][h * DH + c + 3] * kk.w;
      }
      s[h] = a * 0.125f;
    }
  };

  if (nn <= 64) {
    float s[4] = {NEG_BIG, NEG_BIG, NEG_BIG, NEG_BIG};
    if (lane < nn) score4(nbr[wv][lane], s);
    float w[4], l[4];
#pragma unroll
    for (int h = 0; h < 4; ++h) {
      float m = s[h];
      for (int off = 32; off; off >>= 1) m = fmaxf(m, __shfl_down(m, off));
      m = __shfl(m, 0);
      float e = (lane < nn) ? __expf(s[h] - m) : 0.f;
      float ls = e;
      for (int off = 32; off; off >>= 1) ls += __shfl_down(ls, off);
      l[h] = __shfl(ls, 0);
      w[h] = e;
    }
    int i = 0;
    for (; i + 4 <= nn; i += 4) {
      int j0 = nbr[wv][i + 0], j1 = nbr[wv][i + 1];
      int j2 = nbr[wv][i + 2], j3 = nbr[wv][i + 3];
      const float* p0 = base + (size_t)j0 * 768 + 512;
      const float* p1 = base + (size_t)j1 * 768 + 512;
      const float* p2 = base + (size_t)j2 * 768 + 512;
      const float* p3 = base + (size_t)j3 * 768 + 512;
#pragma unroll
      for (int h = 0; h < 4; ++h) {
        acc[h] += __shfl(w[h], i + 0) * p0[h * DH + lane] +
                  __shfl(w[h], i + 1) * p1[h * DH + lane] +
                  __shfl(w[h], i + 2) * p2[h * DH + lane] +
                  __shfl(w[h], i + 3) * p3[h * DH + lane];
      }
    }
    for (; i < nn; ++i) {
      const float* p0 = base + (size_t)nbr[wv][i] * 768 + 512;
#pragma unroll
      for (int h = 0; h < 4; ++h) acc[h] += __shfl(w[h], i) * p0[h * DH + lane];
    }
#pragma unroll
    for (int h = 0; h < 4; ++h) acc[h] /= l[h];
  } else {
    float m[4] = {NEG_BIG, NEG_BIG, NEG_BIG, NEG_BIG};
    for (int i0 = 0; i0 < nn; i0 += 64) {
      float s[4] = {NEG_BIG, NEG_BIG, NEG_BIG, NEG_BIG};
      if (i0 + lane < nn) score4(nbr[wv][i0 + lane], s);
#pragma unroll
      for (int h = 0; h < 4; ++h) m[h] = fmaxf(m[h], s[h]);
    }
#pragma unroll
    for (int h = 0; h < 4; ++h) {
      for (int off = 32; off; off >>= 1) m[h] = fmaxf(m[h], __shfl_down(m[h], off));
      m[h] = __shfl(m[h], 0);
    }
    float l[4] = {0.f, 0.f, 0.f, 0.f};
    for (int i0 = 0; i0 < nn; i0 += 64) {
      float s[4] = {NEG_BIG, NEG_BIG, NEG_BIG, NEG_BIG};
      if (i0 + lane < nn) score4(nbr[wv][i0 + lane], s);
      float e[4];
#pragma unroll
      for (int h = 0; h < 4; ++h) {
        e[h] = (i0 + lane < nn) ? __expf(s[h] - m[h]) : 0.f;
        float ls = e[h];
        for (int off = 32; off; off >>= 1) ls += __shfl_down(ls, off);
        l[h] += __shfl(ls, 0);
      }
      int lim = min(64, nn - i0);
      for (int ii = 0; ii < lim; ++ii) {
        const float* p0 = base + (size_t)nbr[wv][i0 + ii] * 768 + 512;
#pragma unroll
        for (int h = 0; h < 4; ++h) acc[h] += __shfl(e[h], ii) * p0[h * DH + lane];
      }
    }
#pragma unroll
    for (int h = 0; h < 4; ++h) acc[h] /= l[h];
  }
#pragma unroll
  for (int h = 0; h < 4; ++h) {
    float a = acc[h];
    bf16 hi = (bf16)a;
    aos[(size_t)bn * 512 + h * DH + lane] = hi;
    aos[(size_t)bn * 512 + 256 + h * DH + lane] = (bf16)(a - (float)hi);
  }
}

// ---------------------------------------------------------------------------
// epilogue: u = x + proj + bo; out = LN(u)*gamma + beta
// ---------------------------------------------------------------------------
__global__ __launch_bounds__(64) void ln_kernel(const float* __restrict__ x,
                                                const float* __restrict__ proj,
                                                const float* __restrict__ bo,
                                                const float* __restrict__ gamma,
                                                const float* __restrict__ beta,
                                                float* __restrict__ out) {
  int row = blockIdx.x;
  int lane = threadIdx.x;
  size_t base = (size_t)row * D + lane * 4;
  float4 xv = *(const float4*)(x + base);
  float4 pv = *(const float4*)(proj + base);
  float4 bv = *(const float4*)(bo + lane * 4);
  float u0 = xv.x + pv.x + bv.x, u1 = xv.y + pv.y + bv.y;
  float u2 = xv.z + pv.z + bv.z, u3 = xv.w + pv.w + bv.w;
  float s = u0 + u1 + u2 + u3;
  for (int off = 32; off; off >>= 1) s += __shfl_down(s, off);
  s = __shfl(s, 0);
  float mean = s * (1.0f / D);
  float d0 = u0 - mean, d1 = u1 - mean, d2 = u2 - mean, d3 = u3 - mean;
  float ss = d0 * d0 + d1 * d1 + d2 * d2 + d3 * d3;
  for (int off = 32; off; off >>= 1) ss += __shfl_down(ss, off);
  ss = __shfl(ss, 0);
  float rstd = rsqrtf(ss * (1.0f / D) + 1e-5f);
  float4 gv = *(const float4*)(gamma + lane * 4);
  float4 be = *(const float4*)(beta + lane * 4);
  float4 o;
  o.x = d0 * rstd * gv.x + be.x;
  o.y = d1 * rstd * gv.y + be.y;
  o.z = d2 * rstd * gv.z + be.z;
  o.w = d3 * rstd * gv.w + be.w;
  *(float4*)(out + base) = o;
}

// ---------------------------------------------------------------------------
// Workspace (83,132,416 B total — round-3-proven big layout):
//  phase A: XsN [0,12.58M) | sim [12.58M,79.69M) | mask | Wt
//  phase B (XsN+sim dead): XsRaw [0,8.39M) | qkv [8.39M,33.55M)
//                          aos [33.55M,41.94M) | proj [41.94M,50.33M)
// ---------------------------------------------------------------------------
extern "C" void kernel_launch(void* const* d_in, const int* in_sizes, int n_in,
                              void* d_out, int out_size, void* d_ws, size_t ws_size,
                              hipStream_t stream) {
  const float* x     = (const float*)d_in[0];
  const float* Wq    = (const float*)d_in[1];
  const float* Wk    = (const float*)d_in[2];
  const float* Wv    = (const float*)d_in[3];
  const float* Wo    = (const float*)d_in[4];
  const float* bo    = (const float*)d_in[5];
  const float* gamma = (const float*)d_in[6];
  const float* beta  = (const float*)d_in[7];
  float* out = (float*)d_out;

  char* ws = (char*)d_ws;
  bf16* XsN      = (bf16*)(ws);
  float* sim     = (float*)(ws + 12582912);
  unsigned* mask = (unsigned*)(ws + 79986688);
  bf16* Wt       = (bf16*)(ws + 82083840);
  bf16* XsRaw    = (bf16*)(ws);
  float* qkv     = (float*)(ws + 8388608);
  bf16* aos      = (bf16*)(ws + 33554432);
  float* proj    = (float*)(ws + 41943040);

  // 5-chunk sim split: hh, hm, mh, mm, lh (hl dropped — stochastic err ~1e-6
  // vs ~1.3e-2 order-stat gaps).  nsteps = 5 chunks x 4 BK64 steps = 20.
  const int AMAP_SIM = PK6(0, 0, 1, 1, 2, 0);
  const int BMAP_SIM = PK6(0, 1, 0, 1, 0, 0);
  const int AMAP_2T  = PK3(0, 1, 0);
  const int BMAP_2T  = PK3(0, 0, 1);

  (void)hipMemsetAsync(mask, 0, (size_t)BATCH * N * (N / 32) * sizeof(unsigned), stream);
  prep_xn_w_kernel<<<9216, 64, 0, stream>>>(x, Wq, Wk, Wv, Wo, XsN, Wt);

  gemm_bt_kernel<<<dim3(544, 1, 1), 256, 0, stream>>>(
      XsN, XsN, sim, 768, 768, N, 20, AMAP_SIM, BMAP_SIM,
      (long)N * 768, (long)N * 768, (long)N * N, 1);
  topk_adj_kernel<<<BATCH * N, 64, 0, stream>>>(sim, mask);

  prep_raw_kernel<<<BATCH * N, 64, 0, stream>>>(x, XsRaw);
  gemm_bt_kernel<<<dim3(6, 64, 1), 256, 0, stream>>>(
      XsRaw, Wt, qkv, 512, 512, 768, 8, AMAP_2T, BMAP_2T, 0, 0, 0, 0);

  attn_kernel<<<(BATCH * N) / 4, 256, 0, stream>>>(qkv, mask, aos);

  gemm_bt_kernel<<<dim3(2, 64, 1), 256, 0, stream>>>(
      aos, Wt + (size_t)768 * 512, proj, 512, 512, D, 8, AMAP_2T, BMAP_2T, 0, 0, 0, 0);
  ln_kernel<<<BATCH * N, 64, 0, stream>>>(x, proj, bo, gamma, beta, out);
}

// Round 13
// 205.060 us; speedup vs baseline: 1.1355x; 1.0664x over previous
//
#include <hip/hip_runtime.h>
#include <hip/hip_bf16.h>
#include <math.h>

#define BATCH 4
#define N 2048
#define D 256
#define NH 4
#define DH 64
#define TOPK 9
#define NEG_BIG -1e30f

typedef __bf16 bf16;
typedef __bf16 bf16x8 __attribute__((ext_vector_type(8)));
typedef float f32x4 __attribute__((ext_vector_type(4)));

#define PK3(a,b,c) ((a) | ((b) << 2) | ((c) << 4))
#define PK6(a,b,c,d,e,f) ((a) | ((b) << 2) | ((c) << 4) | ((d) << 6) | ((e) << 8) | ((f) << 10))

// s_waitcnt with ONLY vmcnt=N (lgkmcnt=15/expcnt=7 = no wait). gfx9 encoding:
// vmcnt[3:0]@0, expcnt@4, lgkmcnt@8, vmcnt[5:4]@14.
#define WAITVM(Nc) __builtin_amdgcn_s_waitcnt((((Nc) & 0xf)) | (7u << 4) | (0xfu << 8) | ((((unsigned)(Nc)) >> 4) << 14))

__device__ __forceinline__ void async_cp16(const bf16* g, const bf16* l) {
  __builtin_amdgcn_global_load_lds(
      (const __attribute__((address_space(1))) void*)(uintptr_t)g,
      (__attribute__((address_space(3))) void*)(uintptr_t)l, 16, 0, 0);
}

// ---------------------------------------------------------------------------
// prep: blk<8192: x -> XsN (L2-norm, 3-way split, stride 768)
//       blk<9216: W{q,k,v,o} -> Wt (transpose + 2-way split)
//       else (128 blks): zero the 2 MB adjacency mask (replaces memset)
// ---------------------------------------------------------------------------
__global__ __launch_bounds__(64) void prep_xn_w_kernel(const float* __restrict__ x,
                                                       const float* __restrict__ Wq,
                                                       const float* __restrict__ Wk,
                                                       const float* __restrict__ Wv,
                                                       const float* __restrict__ Wo,
                                                       bf16* __restrict__ XsN,
                                                       bf16* __restrict__ Wt,
                                                       uint4* __restrict__ mask4) {
  int blk = blockIdx.x;
  int lane = threadIdx.x;
  if (blk < 8192) {
    float4 v = *(const float4*)(x + (size_t)blk * D + lane * 4);
    float ss = v.x * v.x + v.y * v.y + v.z * v.z + v.w * v.w;
    for (int off = 32; off; off >>= 1) ss += __shfl_down(ss, off);
    ss = __shfl(ss, 0);
    float sc = 1.0f / fmaxf(sqrtf(ss), 1e-12f);
    float xs[4] = {v.x * sc, v.y * sc, v.z * sc, v.w * sc};
    bf16* o = XsN + (size_t)blk * 768 + lane * 4;
#pragma unroll
    for (int j = 0; j < 4; ++j) {
      float xv = xs[j];
      bf16 h = (bf16)xv;
      float r1 = xv - (float)h;
      bf16 m = (bf16)r1;
      o[j] = h;
      o[256 + j] = m;
      o[512 + j] = (bf16)(r1 - (float)m);
    }
  } else if (blk < 9216) {
    int jj = blk - 8192;
    const float* W = (jj < 256) ? Wq : (jj < 512) ? Wk : (jj < 768) ? Wv : Wo;
    int j = jj & 255;
    bf16* dst = Wt + (size_t)jj * 512;
    for (int k = lane; k < 256; k += 64) {
      float w = W[(size_t)k * D + j];
      bf16 h = (bf16)w;
      dst[k] = h;
      dst[256 + k] = (bf16)(w - (float)h);
    }
  } else {
    // zero mask: 2,097,152 B = 131072 uint4; 128 blocks x 64 lanes x 16 uint4
    int base = (blk - 9216) * 1024 + lane;
#pragma unroll
    for (int t = 0; t < 16; ++t)
      mask4[base + t * 64] = make_uint4(0, 0, 0, 0);
  }
}

// prep phase 2: x -> XsRaw (2-way split, stride 512) — runs after sim is dead
__global__ __launch_bounds__(64) void prep_raw_kernel(const float* __restrict__ x,
                                                      bf16* __restrict__ XsRaw) {
  int row = blockIdx.x;
  int lane = threadIdx.x;
  float4 v = *(const float4*)(x + (size_t)row * D + lane * 4);
  float xs[4] = {v.x, v.y, v.z, v.w};
  bf16* o = XsRaw + (size_t)row * 512 + lane * 4;
#pragma unroll
  for (int j = 0; j < 4; ++j) {
    bf16 h = (bf16)xs[j];
    o[j] = h;
    o[256 + j] = (bf16)(xs[j] - (float)h);
  }
}

// ---------------------------------------------------------------------------
// MFMA GEMM — round-8 proven structure: BK=64, LDS double-buffer (64 KB,
// 2 blocks/CU), global_load_lds staging, raw s_barrier + vmcnt(8), XOR
// swizzle key (row&7) (verified 0 conflicts, rounds 7-8).
// mode 0: generic C = A@B^T, grid (Nc/128, M/128, batches).
// mode 1: symmetric sim = A@A^T, grid (544,1,1), XCD-aware triangular decode
//         (FETCH 124->14 MB, round 8); nontemporal C stores (incl. mirror).
// ---------------------------------------------------------------------------
__global__ __launch_bounds__(256) void gemm_bt_kernel(const bf16* __restrict__ A,
                                                      const bf16* __restrict__ B,
                                                      float* __restrict__ C,
                                                      int lda, int ldb, int ldc,
                                                      int nsteps, int amap, int bmap,
                                                      long sA, long sB, long sC,
                                                      int mode) {
  __shared__ bf16 As[2][128 * 64];
  __shared__ bf16 Bs[2][128 * 64];
  int tid = threadIdx.x;
  int lane = tid & 63;
  int wv = tid >> 6;
  int wm = (wv >> 1) * 64;
  int wn = (wv & 1) * 64;
  int bx, by, z;
  if (mode) {  // XCD-aware triangular decode
    int g = blockIdx.x;
    int xcd = g & 7;
    int slot = g >> 3;          // 0..67
    z = xcd >> 1;
    int t = (xcd & 1) * 68 + slot;  // pair 0..135
    by = 0;
    while (t >= 16 - by) { t -= 16 - by; ++by; }
    bx = by + t;
  } else {
    bx = blockIdx.x;
    by = blockIdx.y;
    z = blockIdx.z;
  }
  int row0 = by * 128;
  int col0 = bx * 128;
  const bf16* Ab = A + (size_t)z * sA + (size_t)row0 * lda;
  const bf16* Bb = B + (size_t)z * sB + (size_t)col0 * ldb;
  float* Cb = C + (size_t)z * sC;

  int rbase = tid >> 3;
  int gperm = (tid & 7) ^ (rbase & 7);
  const bf16* ga0 = Ab + (size_t)rbase * lda + gperm * 8;
  const bf16* gb0 = Bb + (size_t)rbase * ldb + gperm * 8;
  int ldsoff = tid * 8;  // 16 B per thread

  int fr = lane & 15;
  int fq = (lane >> 4) * 8;

  f32x4 acc[4][4] = {};

  auto issue = [&](int st, int buf) {
    int ch = st >> 2;
    int aoff = (((amap >> (ch * 2)) & 3) << 8) | ((st & 3) << 6);
    int boff = (((bmap >> (ch * 2)) & 3) << 8) | ((st & 3) << 6);
#pragma unroll
    for (int q = 0; q < 4; ++q)
      async_cp16(ga0 + (size_t)q * 32 * lda + aoff, &As[buf][ldsoff + q * 2048]);
#pragma unroll
    for (int q = 0; q < 4; ++q)
      async_cp16(gb0 + (size_t)q * 32 * ldb + boff, &Bs[buf][ldsoff + q * 2048]);
  };

  issue(0, 0);
  for (int st = 0; st < nsteps; ++st) {
    int buf = st & 1;
    if (st + 1 < nsteps) {
      issue(st + 1, buf ^ 1);
      WAITVM(8);   // in-order retire: <=8 outstanding => buf st fully landed
    } else {
      WAITVM(0);
    }
    __builtin_amdgcn_s_barrier();  // all waves' staging for buf visible
#pragma unroll
    for (int ks = 0; ks < 64; ks += 32) {
      bf16x8 af[4], bfr[4];
#pragma unroll
      for (int mi = 0; mi < 4; ++mi) {
        int r = wm + mi * 16 + fr;
        int G = (ks + fq) >> 3;
        af[mi] = *(const bf16x8*)&As[buf][r * 64 + ((G ^ (r & 7)) << 3)];
      }
#pragma unroll
      for (int nj = 0; nj < 4; ++nj) {
        int r = wn + nj * 16 + fr;
        int G = (ks + fq) >> 3;
        bfr[nj] = *(const bf16x8*)&Bs[buf][r * 64 + ((G ^ (r & 7)) << 3)];
      }
#pragma unroll
      for (int mi = 0; mi < 4; ++mi)
#pragma unroll
        for (int nj = 0; nj < 4; ++nj)
          acc[mi][nj] = __builtin_amdgcn_mfma_f32_16x16x32_bf16(af[mi], bfr[nj], acc[mi][nj], 0, 0, 0);
    }
    __builtin_amdgcn_s_barrier();  // reads of buf done before st+2 overwrites it
  }

  int er = (lane >> 4) * 4;
  int ec = lane & 15;
#pragma unroll
  for (int mi = 0; mi < 4; ++mi)
#pragma unroll
    for (int nj = 0; nj < 4; ++nj) {
      int rb = row0 + wm + mi * 16 + er;
      int cb = col0 + wn + nj * 16 + ec;
      if (mode) {
#pragma unroll
        for (int reg = 0; reg < 4; ++reg)
          __builtin_nontemporal_store(acc[mi][nj][reg],
                                      &Cb[(size_t)(rb + reg) * ldc + cb]);
        if (bx != by) {
#pragma unroll
          for (int reg = 0; reg < 4; ++reg)
            __builtin_nontemporal_store(acc[mi][nj][reg],
                                        &Cb[(size_t)cb * ldc + rb + reg]);
        }
      } else {
#pragma unroll
        for (int reg = 0; reg < 4; ++reg)
          Cb[(size_t)(rb + reg) * ldc + cb] = acc[mi][nj][reg];
      }
    }
}

// ---------------------------------------------------------------------------
// top-9 per row by 9x extract-max (branch-free masked argmax in registers),
// fused adjacency write. One wave per row; mask pre-zeroed.
// Selection set identical to lax.top_k: (value desc, index asc) tie-break.
// ---------------------------------------------------------------------------
__global__ __launch_bounds__(64) void topk_adj_kernel(const float* __restrict__ sim,
                                                      unsigned* __restrict__ mask) {
  int row = blockIdx.x;
  int lane = threadIdx.x;
  int b = row >> 11, r = row & 2047;
  const float* srow = sim + (size_t)row * N;
  float v[32];
#pragma unroll
  for (int it = 0; it < 8; ++it) {
    float4 q = *(const float4*)(srow + it * 256 + lane * 4);
    v[it * 4 + 0] = q.x; v[it * 4 + 1] = q.y;
    v[it * 4 + 2] = q.z; v[it * 4 + 3] = q.w;
  }
  unsigned removed = 0;
  for (int rs = 0; rs < TOPK; ++rs) {
    float m = -3e38f;
    int mi = 0;
#pragma unroll
    for (int i = 0; i < 32; ++i) {
      float vv = ((removed >> i) & 1u) ? -3e38f : v[i];
      if (vv > m) { m = vv; mi = i; }  // ascending i = ascending global idx
    }
    int gidx = ((mi >> 2) << 8) + lane * 4 + (mi & 3);
    for (int off = 32; off; off >>= 1) {
      float om = __shfl_down(m, off);
      int og = __shfl_down(gidx, off);
      if (om > m || (om == m && og < gidx)) { m = om; gidx = og; }
    }
    gidx = __shfl(gidx, 0);
    if (((gidx >> 2) & 63) == lane)
      removed |= 1u << (((gidx >> 8) << 2) | (gidx & 3));
    if (lane == 0) {
      atomicOr(&mask[(size_t)row * 64 + (gidx >> 5)], 1u << (gidx & 31));
      atomicOr(&mask[(((size_t)b << 11) + gidx) * 64 + (r >> 5)], 1u << (r & 31));
    }
  }
}

// ---------------------------------------------------------------------------
// sparse attention: 4 waves/block, one (b,n) row per wave; XCD-aware decode
// (batch b -> XCDs {2b,2b+1}: per-XCD gather working set 25 MB -> 6.3 MB);
// writes bf16-split aos (stride 512) directly.
// ---------------------------------------------------------------------------
__global__ __launch_bounds__(256) void attn_kernel(const float* __restrict__ qkv,
                                                   const unsigned* __restrict__ mask,
                                                   bf16* __restrict__ aos) {
  __shared__ float sq[4][256];
  __shared__ unsigned short nbr[4][2048];
  __shared__ int s_nn[4];
  int wv = threadIdx.x >> 6;
  int lane = threadIdx.x & 63;
  int g = blockIdx.x;
  int xcd = g & 7;
  int b = xcd >> 1;
  int tile = (xcd & 1) * 256 + (g >> 3);  // 0..511
  int bn = b * N + tile * 4 + wv;
  if (lane == 0) s_nn[wv] = 0;
  *(float4*)&sq[wv][lane * 4] = *(const float4*)(qkv + (size_t)bn * 768 + lane * 4);
  __syncthreads();
  unsigned bits = mask[(size_t)bn * (N / 32) + lane];
  while (bits) {
    int bit = __ffs(bits) - 1;
    bits &= bits - 1;
    int p = atomicAdd(&s_nn[wv], 1);
    nbr[wv][p] = (unsigned short)(lane * 32 + bit);
  }
  __syncthreads();
  int nn = s_nn[wv];
  const float* base = qkv + (size_t)b * N * 768;
  float acc[4] = {0.f, 0.f, 0.f, 0.f};

  auto score4 = [&](int j, float* s) {
    const float* kr = base + (size_t)j * 768 + 256;
#pragma unroll
    for (int h = 0; h < 4; ++h) {
      float a = 0.f;
#pragma unroll
      for (int c = 0; c < DH; c += 4) {
        float4 kk = *(const float4*)(kr + h * DH + c);
        a += sq[wv][h * DH + c] * kk.x + sq[wv][h * DH + c + 1] * kk.y +
             sq[wv][h * DH + c + 2] * kk.z + sq[wv][h * DH + c + 3] * kk.w;
      }
      s[h] = a * 0.125f;
    }
  };

  if (nn <= 64) {
    float s[4] = {NEG_BIG, NEG_BIG, NEG_BIG, NEG_BIG};
    if (lane < nn) score4(nbr[wv][lane], s);
    float w[4], l[4];
#pragma unroll
    for (int h = 0; h < 4; ++h) {
      float m = s[h];
      for (int off = 32; off; off >>= 1) m = fmaxf(m, __shfl_down(m, off));
      m = __shfl(m, 0);
      float e = (lane < nn) ? __expf(s[h] - m) : 0.f;
      float ls = e;
      for (int off = 32; off; off >>= 1) ls += __shfl_down(ls, off);
      l[h] = __shfl(ls, 0);
      w[h] = e;
    }
    int i = 0;
    for (; i + 4 <= nn; i += 4) {
      int j0 = nbr[wv][i + 0], j1 = nbr[wv][i + 1];
      int j2 = nbr[wv][i + 2], j3 = nbr[wv][i + 3];
      const float* p0 = base + (size_t)j0 * 768 + 512;
      const float* p1 = base + (size_t)j1 * 768 + 512;
      const float* p2 = base + (size_t)j2 * 768 + 512;
      const float* p3 = base + (size_t)j3 * 768 + 512;
#pragma unroll
      for (int h = 0; h < 4; ++h) {
        acc[h] += __shfl(w[h], i + 0) * p0[h * DH + lane] +
                  __shfl(w[h], i + 1) * p1[h * DH + lane] +
                  __shfl(w[h], i + 2) * p2[h * DH + lane] +
                  __shfl(w[h], i + 3) * p3[h * DH + lane];
      }
    }
    for (; i < nn; ++i) {
      const float* p0 = base + (size_t)nbr[wv][i] * 768 + 512;
#pragma unroll
      for (int h = 0; h < 4; ++h) acc[h] += __shfl(w[h], i) * p0[h * DH + lane];
    }
#pragma unroll
    for (int h = 0; h < 4; ++h) acc[h] /= l[h];
  } else {
    float m[4] = {NEG_BIG, NEG_BIG, NEG_BIG, NEG_BIG};
    for (int i0 = 0; i0 < nn; i0 += 64) {
      float s[4] = {NEG_BIG, NEG_BIG, NEG_BIG, NEG_BIG};
      if (i0 + lane < nn) score4(nbr[wv][i0 + lane], s);
#pragma unroll
      for (int h = 0; h < 4; ++h) m[h] = fmaxf(m[h], s[h]);
    }
#pragma unroll
    for (int h = 0; h < 4; ++h) {
      for (int off = 32; off; off >>= 1) m[h] = fmaxf(m[h], __shfl_down(m[h], off));
      m[h] = __shfl(m[h], 0);
    }
    float l[4] = {0.f, 0.f, 0.f, 0.f};
    for (int i0 = 0; i0 < nn; i0 += 64) {
      float s[4] = {NEG_BIG, NEG_BIG, NEG_BIG, NEG_BIG};
      if (i0 + lane < nn) score4(nbr[wv][i0 + lane], s);
      float e[4];
#pragma unroll
      for (int h = 0; h < 4; ++h) {
        e[h] = (i0 + lane < nn) ? __expf(s[h] - m[h]) : 0.f;
        float ls = e[h];
        for (int off = 32; off; off >>= 1) ls += __shfl_down(ls, off);
        l[h] += __shfl(ls, 0);
      }
      int lim = min(64, nn - i0);
      for (int ii = 0; ii < lim; ++ii) {
        const float* p0 = base + (size_t)nbr[wv][i0 + ii] * 768 + 512;
#pragma unroll
        for (int h = 0; h < 4; ++h) acc[h] += __shfl(e[h], ii) * p0[h * DH + lane];
      }
    }
#pragma unroll
    for (int h = 0; h < 4; ++h) acc[h] /= l[h];
  }
#pragma unroll
  for (int h = 0; h < 4; ++h) {
    float a = acc[h];
    bf16 hi = (bf16)a;
    aos[(size_t)bn * 512 + h * DH + lane] = hi;
    aos[(size_t)bn * 512 + 256 + h * DH + lane] = (bf16)(a - (float)hi);
  }
}

// ---------------------------------------------------------------------------
// epilogue: u = x + proj + bo; out = LN(u)*gamma + beta
// ---------------------------------------------------------------------------
__global__ __launch_bounds__(64) void ln_kernel(const float* __restrict__ x,
                                                const float* __restrict__ proj,
                                                const float* __restrict__ bo,
                                                const float* __restrict__ gamma,
                                                const float* __restrict__ beta,
                                                float* __restrict__ out) {
  int row = blockIdx.x;
  int lane = threadIdx.x;
  size_t base = (size_t)row * D + lane * 4;
  float4 xv = *(const float4*)(x + base);
  float4 pv = *(const float4*)(proj + base);
  float4 bv = *(const float4*)(bo + lane * 4);
  float u0 = xv.x + pv.x + bv.x, u1 = xv.y + pv.y + bv.y;
  float u2 = xv.z + pv.z + bv.z, u3 = xv.w + pv.w + bv.w;
  float s = u0 + u1 + u2 + u3;
  for (int off = 32; off; off >>= 1) s += __shfl_down(s, off);
  s = __shfl(s, 0);
  float mean = s * (1.0f / D);
  float d0 = u0 - mean, d1 = u1 - mean, d2 = u2 - mean, d3 = u3 - mean;
  float ss = d0 * d0 + d1 * d1 + d2 * d2 + d3 * d3;
  for (int off = 32; off; off >>= 1) ss += __shfl_down(ss, off);
  ss = __shfl(ss, 0);
  float rstd = rsqrtf(ss * (1.0f / D) + 1e-5f);
  float4 gv = *(const float4*)(gamma + lane * 4);
  float4 be = *(const float4*)(beta + lane * 4);
  float4 o;
  o.x = d0 * rstd * gv.x + be.x;
  o.y = d1 * rstd * gv.y + be.y;
  o.z = d2 * rstd * gv.z + be.z;
  o.w = d3 * rstd * gv.w + be.w;
  *(float4*)(out + base) = o;
}

// ---------------------------------------------------------------------------
// Workspace (83,132,416 B total — round-3-proven big layout):
//  phase A: XsN [0,12.58M) | sim [12.58M,79.69M) | mask | Wt
//  phase B (XsN+sim dead): XsRaw [0,8.39M) | qkv [8.39M,33.55M)
//                          aos [33.55M,41.94M) | proj [41.94M,50.33M)
// ---------------------------------------------------------------------------
extern "C" void kernel_launch(void* const* d_in, const int* in_sizes, int n_in,
                              void* d_out, int out_size, void* d_ws, size_t ws_size,
                              hipStream_t stream) {
  const float* x     = (const float*)d_in[0];
  const float* Wq    = (const float*)d_in[1];
  const float* Wk    = (const float*)d_in[2];
  const float* Wv    = (const float*)d_in[3];
  const float* Wo    = (const float*)d_in[4];
  const float* bo    = (const float*)d_in[5];
  const float* gamma = (const float*)d_in[6];
  const float* beta  = (const float*)d_in[7];
  float* out = (float*)d_out;

  char* ws = (char*)d_ws;
  bf16* XsN      = (bf16*)(ws);
  float* sim     = (float*)(ws + 12582912);
  unsigned* mask = (unsigned*)(ws + 79986688);
  bf16* Wt       = (bf16*)(ws + 82083840);
  bf16* XsRaw    = (bf16*)(ws);
  float* qkv     = (float*)(ws + 8388608);
  bf16* aos      = (bf16*)(ws + 33554432);
  float* proj    = (float*)(ws + 41943040);

  // 3-chunk sim split: hh + hm + mh (mm/lh/hl dropped — combined err ~3e-7
  // vs 1.3e-2 order-stat gaps).  nsteps = 3 x 4 = 12.
  const int AMAP_SIM = PK6(0, 0, 1, 0, 0, 0);
  const int BMAP_SIM = PK6(0, 1, 0, 0, 0, 0);
  const int AMAP_2T  = PK3(0, 1, 0);
  const int BMAP_2T  = PK3(0, 0, 1);

  prep_xn_w_kernel<<<9344, 64, 0, stream>>>(x, Wq, Wk, Wv, Wo, XsN, Wt,
                                            (uint4*)mask);

  gemm_bt_kernel<<<dim3(544, 1, 1), 256, 0, stream>>>(
      XsN, XsN, sim, 768, 768, N, 12, AMAP_SIM, BMAP_SIM,
      (long)N * 768, (long)N * 768, (long)N * N, 1);
  topk_adj_kernel<<<BATCH * N, 64, 0, stream>>>(sim, mask);

  prep_raw_kernel<<<BATCH * N, 64, 0, stream>>>(x, XsRaw);
  gemm_bt_kernel<<<dim3(6, 64, 1), 256, 0, stream>>>(
      XsRaw, Wt, qkv, 512, 512, 768, 8, AMAP_2T, BMAP_2T, 0, 0, 0, 0);

  attn_kernel<<<(BATCH * N) / 4, 256, 0, stream>>>(qkv, mask, aos);

  gemm_bt_kernel<<<dim3(2, 64, 1), 256, 0, stream>>>(
      aos, Wt + (size_t)768 * 512, proj, 512, 512, D, 8, AMAP_2T, BMAP_2T, 0, 0, 0, 0);
  ln_kernel<<<BATCH * N, 64, 0, stream>>>(x, proj, bo, gamma, beta, out);
}

// Round 14
// 198.701 us; speedup vs baseline: 1.1718x; 1.0320x over previous
//
#include <hip/hip_runtime.h>
#include <hip/hip_bf16.h>
#include <math.h>

#define BATCH 4
#define N 2048
#define D 256
#define NH 4
#define DH 64
#define TOPK 9
#define NEG_BIG -1e30f

typedef __bf16 bf16;
typedef __bf16 bf16x8 __attribute__((ext_vector_type(8)));
typedef float f32x4 __attribute__((ext_vector_type(4)));

#define PK3(a,b,c) ((a) | ((b) << 2) | ((c) << 4))
#define PK6(a,b,c,d,e,f) ((a) | ((b) << 2) | ((c) << 4) | ((d) << 6) | ((e) << 8) | ((f) << 10))

// s_waitcnt with ONLY vmcnt=N (lgkmcnt=15/expcnt=7 = no wait). gfx9 encoding:
// vmcnt[3:0]@0, expcnt@4, lgkmcnt@8, vmcnt[5:4]@14.
#define WAITVM(Nc) __builtin_amdgcn_s_waitcnt((((Nc) & 0xf)) | (7u << 4) | (0xfu << 8) | ((((unsigned)(Nc)) >> 4) << 14))

__device__ __forceinline__ void async_cp16(const bf16* g, const bf16* l) {
  __builtin_amdgcn_global_load_lds(
      (const __attribute__((address_space(1))) void*)(uintptr_t)g,
      (__attribute__((address_space(3))) void*)(uintptr_t)l, 16, 0, 0);
}

// ---------------------------------------------------------------------------
// prep: blk<8192: x -> XsN (L2-norm, 3-way split, stride 768) + norms[row]
//       blk<9216: W{q,k,v,o} -> Wt (transpose + 2-way split)
//       else (128 blks): zero the 2 MB adjacency mask
// ---------------------------------------------------------------------------
__global__ __launch_bounds__(64) void prep_kernel(const float* __restrict__ x,
                                                  const float* __restrict__ Wq,
                                                  const float* __restrict__ Wk,
                                                  const float* __restrict__ Wv,
                                                  const float* __restrict__ Wo,
                                                  bf16* __restrict__ XsN,
                                                  bf16* __restrict__ Wt,
                                                  float* __restrict__ norms,
                                                  uint4* __restrict__ mask4) {
  int blk = blockIdx.x;
  int lane = threadIdx.x;
  if (blk < 8192) {
    float4 v = *(const float4*)(x + (size_t)blk * D + lane * 4);
    float ss = v.x * v.x + v.y * v.y + v.z * v.z + v.w * v.w;
    for (int off = 32; off; off >>= 1) ss += __shfl_down(ss, off);
    ss = __shfl(ss, 0);
    float nrm = fmaxf(sqrtf(ss), 1e-12f);
    if (lane == 0) norms[blk] = nrm;
    float sc = 1.0f / nrm;
    float xs[4] = {v.x * sc, v.y * sc, v.z * sc, v.w * sc};
    bf16* o = XsN + (size_t)blk * 768 + lane * 4;
#pragma unroll
    for (int j = 0; j < 4; ++j) {
      float xv = xs[j];
      bf16 h = (bf16)xv;
      float r1 = xv - (float)h;
      bf16 m = (bf16)r1;
      o[j] = h;
      o[256 + j] = m;
      o[512 + j] = (bf16)(r1 - (float)m);
    }
  } else if (blk < 9216) {
    int jj = blk - 8192;
    const float* W = (jj < 256) ? Wq : (jj < 512) ? Wk : (jj < 768) ? Wv : Wo;
    int j = jj & 255;
    bf16* dst = Wt + (size_t)jj * 512;
    for (int k = lane; k < 256; k += 64) {
      float w = W[(size_t)k * D + j];
      bf16 h = (bf16)w;
      dst[k] = h;
      dst[256 + k] = (bf16)(w - (float)h);
    }
  } else {
    int base = (blk - 9216) * 1024 + lane;
#pragma unroll
    for (int t = 0; t < 16; ++t)
      mask4[base + t * 64] = make_uint4(0, 0, 0, 0);
  }
}

// ---------------------------------------------------------------------------
// GEMM core — round-8 proven structure: BK=64, LDS double-buffer,
// global_load_lds staging, raw s_barrier + vmcnt(8), XOR swizzle (row&7).
// mirror/nt for sim; rowscale for the qkv norm-rescale epilogue.
// ---------------------------------------------------------------------------
__device__ __forceinline__ void gemm_core(bf16* As, bf16* Bs,
                                          const bf16* __restrict__ Ab,
                                          const bf16* __restrict__ Bb,
                                          float* __restrict__ Cb,
                                          int lda, int ldb, int ldc,
                                          int nsteps, int amap, int bmap,
                                          int row0, int col0,
                                          bool mirror, bool nt,
                                          const float* __restrict__ rowscale) {
  int tid = threadIdx.x;
  int lane = tid & 63;
  int wv = tid >> 6;
  int wm = (wv >> 1) * 64;
  int wn = (wv & 1) * 64;

  int rbase = tid >> 3;
  int gperm = (tid & 7) ^ (rbase & 7);
  const bf16* ga0 = Ab + (size_t)rbase * lda + gperm * 8;
  const bf16* gb0 = Bb + (size_t)rbase * ldb + gperm * 8;
  int ldsoff = tid * 8;  // 16 B per thread

  int fr = lane & 15;
  int fq = (lane >> 4) * 8;

  f32x4 acc[4][4] = {};

  auto issue = [&](int st, int buf) {
    int ch = st >> 2;
    int aoff = (((amap >> (ch * 2)) & 3) << 8) | ((st & 3) << 6);
    int boff = (((bmap >> (ch * 2)) & 3) << 8) | ((st & 3) << 6);
#pragma unroll
    for (int q = 0; q < 4; ++q)
      async_cp16(ga0 + (size_t)q * 32 * lda + aoff, &As[buf * 8192 + ldsoff + q * 2048]);
#pragma unroll
    for (int q = 0; q < 4; ++q)
      async_cp16(gb0 + (size_t)q * 32 * ldb + boff, &Bs[buf * 8192 + ldsoff + q * 2048]);
  };

  issue(0, 0);
  for (int st = 0; st < nsteps; ++st) {
    int buf = st & 1;
    if (st + 1 < nsteps) {
      issue(st + 1, buf ^ 1);
      WAITVM(8);   // in-order retire: <=8 outstanding => buf st fully landed
    } else {
      WAITVM(0);
    }
    __builtin_amdgcn_s_barrier();  // all waves' staging for buf visible
#pragma unroll
    for (int ks = 0; ks < 64; ks += 32) {
      bf16x8 af[4], bfr[4];
#pragma unroll
      for (int mi = 0; mi < 4; ++mi) {
        int r = wm + mi * 16 + fr;
        int G = (ks + fq) >> 3;
        af[mi] = *(const bf16x8*)&As[buf * 8192 + r * 64 + ((G ^ (r & 7)) << 3)];
      }
#pragma unroll
      for (int nj = 0; nj < 4; ++nj) {
        int r = wn + nj * 16 + fr;
        int G = (ks + fq) >> 3;
        bfr[nj] = *(const bf16x8*)&Bs[buf * 8192 + r * 64 + ((G ^ (r & 7)) << 3)];
      }
#pragma unroll
      for (int mi = 0; mi < 4; ++mi)
#pragma unroll
        for (int nj = 0; nj < 4; ++nj)
          acc[mi][nj] = __builtin_amdgcn_mfma_f32_16x16x32_bf16(af[mi], bfr[nj], acc[mi][nj], 0, 0, 0);
    }
    __builtin_amdgcn_s_barrier();  // reads of buf done before st+2 overwrites it
  }

  int er = (lane >> 4) * 4;
  int ec = lane & 15;
#pragma unroll
  for (int mi = 0; mi < 4; ++mi) {
    int rb = row0 + wm + mi * 16 + er;
    float scl[4] = {1.f, 1.f, 1.f, 1.f};
    if (rowscale) {
      float4 s4 = *(const float4*)(rowscale + rb);
      scl[0] = s4.x; scl[1] = s4.y; scl[2] = s4.z; scl[3] = s4.w;
    }
#pragma unroll
    for (int nj = 0; nj < 4; ++nj) {
      int cb = col0 + wn + nj * 16 + ec;
      if (nt) {
#pragma unroll
        for (int reg = 0; reg < 4; ++reg)
          __builtin_nontemporal_store(acc[mi][nj][reg],
                                      &Cb[(size_t)(rb + reg) * ldc + cb]);
        if (mirror) {
#pragma unroll
          for (int reg = 0; reg < 4; ++reg)
            __builtin_nontemporal_store(acc[mi][nj][reg],
                                        &Cb[(size_t)cb * ldc + rb + reg]);
        }
      } else {
#pragma unroll
        for (int reg = 0; reg < 4; ++reg)
          Cb[(size_t)(rb + reg) * ldc + cb] = acc[mi][nj][reg] * scl[reg];
      }
    }
  }
}

// sim-only dispatch (small-ws fallback): grid (544)
__global__ __launch_bounds__(256) void gemm_sim_kernel(const bf16* __restrict__ XsN,
                                                       float* __restrict__ sim,
                                                       int amap, int bmap) {
  __shared__ bf16 As[2 * 128 * 64];
  __shared__ bf16 Bs[2 * 128 * 64];
  int g = blockIdx.x;
  int xcd = g & 7;
  int slot = g >> 3;
  int z = xcd >> 1;
  int t = (xcd & 1) * 68 + slot;
  int by = 0;
  while (t >= 16 - by) { t -= 16 - by; ++by; }
  int bx = by + t;
  gemm_core(As, Bs,
            XsN + (size_t)z * N * 768 + (size_t)by * 128 * 768,
            XsN + (size_t)z * N * 768 + (size_t)bx * 128 * 768,
            sim + (size_t)z * N * N,
            768, 768, N, 12, amap, bmap, by * 128, bx * 128,
            bx != by, true, nullptr);
}

// generic dispatch: grid (nbx, nby)
__global__ __launch_bounds__(256) void gemm_gen_kernel(const bf16* __restrict__ A,
                                                       const bf16* __restrict__ B,
                                                       float* __restrict__ C,
                                                       int lda, int ldb, int ldc,
                                                       int nsteps, int amap, int bmap,
                                                       const float* __restrict__ rowscale) {
  __shared__ bf16 As[2 * 128 * 64];
  __shared__ bf16 Bs[2 * 128 * 64];
  gemm_core(As, Bs,
            A + (size_t)blockIdx.y * 128 * lda,
            B + (size_t)blockIdx.x * 128 * ldb,
            C, lda, ldb, ldc, nsteps, amap, bmap,
            blockIdx.y * 128, blockIdx.x * 128, false, false, rowscale);
}

// fused sim + qkv dispatch (big-ws path): grid (928)
__global__ __launch_bounds__(256) void gemm_fused_kernel(const bf16* __restrict__ XsN,
                                                         float* __restrict__ sim,
                                                         int amap_s, int bmap_s,
                                                         const bf16* __restrict__ Wt,
                                                         float* __restrict__ qkv,
                                                         int amap_q, int bmap_q,
                                                         const float* __restrict__ norms) {
  __shared__ bf16 As[2 * 128 * 64];
  __shared__ bf16 Bs[2 * 128 * 64];
  int g = blockIdx.x;
  if (g < 544) {
    int xcd = g & 7;
    int slot = g >> 3;
    int z = xcd >> 1;
    int t = (xcd & 1) * 68 + slot;
    int by = 0;
    while (t >= 16 - by) { t -= 16 - by; ++by; }
    int bx = by + t;
    gemm_core(As, Bs,
              XsN + (size_t)z * N * 768 + (size_t)by * 128 * 768,
              XsN + (size_t)z * N * 768 + (size_t)bx * 128 * 768,
              sim + (size_t)z * N * N,
              768, 768, N, 12, amap_s, bmap_s, by * 128, bx * 128,
              bx != by, true, nullptr);
  } else {
    int t = g - 544;
    int bx = t % 6;
    int by = t / 6;
    gemm_core(As, Bs,
              XsN + (size_t)by * 128 * 768,
              Wt + (size_t)bx * 128 * 512,
              qkv, 768, 512, 768, 8, amap_q, bmap_q,
              by * 128, bx * 128, false, false, norms);
  }
}

// ---------------------------------------------------------------------------
// top-9 per row by 9x extract-max, fused adjacency write.  One wave per row;
// mask pre-zeroed.  Selection set identical to lax.top_k.
// ---------------------------------------------------------------------------
__global__ __launch_bounds__(64) void topk_adj_kernel(const float* __restrict__ sim,
                                                      unsigned* __restrict__ mask) {
  int row = blockIdx.x;
  int lane = threadIdx.x;
  int b = row >> 11, r = row & 2047;
  const float* srow = sim + (size_t)row * N;
  float v[32];
#pragma unroll
  for (int it = 0; it < 8; ++it) {
    float4 q = *(const float4*)(srow + it * 256 + lane * 4);
    v[it * 4 + 0] = q.x; v[it * 4 + 1] = q.y;
    v[it * 4 + 2] = q.z; v[it * 4 + 3] = q.w;
  }
  unsigned removed = 0;
  for (int rs = 0; rs < TOPK; ++rs) {
    float m = -3e38f;
    int mi = 0;
#pragma unroll
    for (int i = 0; i < 32; ++i) {
      float vv = ((removed >> i) & 1u) ? -3e38f : v[i];
      if (vv > m) { m = vv; mi = i; }
    }
    int gidx = ((mi >> 2) << 8) + lane * 4 + (mi & 3);
    for (int off = 32; off; off >>= 1) {
      float om = __shfl_down(m, off);
      int og = __shfl_down(gidx, off);
      if (om > m || (om == m && og < gidx)) { m = om; gidx = og; }
    }
    gidx = __shfl(gidx, 0);
    if (((gidx >> 2) & 63) == lane)
      removed |= 1u << (((gidx >> 8) << 2) | (gidx & 3));
    if (lane == 0) {
      atomicOr(&mask[(size_t)row * 64 + (gidx >> 5)], 1u << (gidx & 31));
      atomicOr(&mask[(((size_t)b << 11) + gidx) * 64 + (r >> 5)], 1u << (r & 31));
    }
  }
}

// ---------------------------------------------------------------------------
// sparse attention: 4 waves/block, one (b,n) row per wave; XCD-aware decode;
// writes bf16-split aos (stride 512) directly.
// ---------------------------------------------------------------------------
__global__ __launch_bounds__(256) void attn_kernel(const float* __restrict__ qkv,
                                                   const unsigned* __restrict__ mask,
                                                   bf16* __restrict__ aos) {
  __shared__ float sq[4][256];
  __shared__ unsigned short nbr[4][2048];
  __shared__ int s_nn[4];
  int wv = threadIdx.x >> 6;
  int lane = threadIdx.x & 63;
  int g = blockIdx.x;
  int xcd = g & 7;
  int b = xcd >> 1;
  int tile = (xcd & 1) * 256 + (g >> 3);
  int bn = b * N + tile * 4 + wv;
  if (lane == 0) s_nn[wv] = 0;
  *(float4*)&sq[wv][lane * 4] = *(const float4*)(qkv + (size_t)bn * 768 + lane * 4);
  __syncthreads();
  unsigned bits = mask[(size_t)bn * (N / 32) + lane];
  while (bits) {
    int bit = __ffs(bits) - 1;
    bits &= bits - 1;
    int p = atomicAdd(&s_nn[wv], 1);
    nbr[wv][p] = (unsigned short)(lane * 32 + bit);
  }
  __syncthreads();
  int nn = s_nn[wv];
  const float* base = qkv + (size_t)b * N * 768;
  float acc[4] = {0.f, 0.f, 0.f, 0.f};

  auto score4 = [&](int j, float* s) {
    const float* kr = base + (size_t)j * 768 + 256;
#pragma unroll
    for (int h = 0; h < 4; ++h) {
      float a = 0.f;
#pragma unroll
      for (int c = 0; c < DH; c += 4) {
        float4 kk = *(const float4*)(kr + h * DH + c);
        a += sq[wv][h * DH + c] * kk.x + sq[wv][h * DH + c + 1] * kk.y +
             sq[wv][h * DH + c + 2] * kk.z + sq[wv][h * DH + c + 3] * kk.w;
      }
      s[h] = a * 0.125f;
    }
  };

  if (nn <= 64) {
    float s[4] = {NEG_BIG, NEG_BIG, NEG_BIG, NEG_BIG};
    if (lane < nn) score4(nbr[wv][lane], s);
    float w[4], l[4];
#pragma unroll
    for (int h = 0; h < 4; ++h) {
      float m = s[h];
      for (int off = 32; off; off >>= 1) m = fmaxf(m, __shfl_down(m, off));
      m = __shfl(m, 0);
      float e = (lane < nn) ? __expf(s[h] - m) : 0.f;
      float ls = e;
      for (int off = 32; off; off >>= 1) ls += __shfl_down(ls, off);
      l[h] = __shfl(ls, 0);
      w[h] = e;
    }
    int i = 0;
    for (; i + 4 <= nn; i += 4) {
      int j0 = nbr[wv][i + 0], j1 = nbr[wv][i + 1];
      int j2 = nbr[wv][i + 2], j3 = nbr[wv][i + 3];
      const float* p0 = base + (size_t)j0 * 768 + 512;
      const float* p1 = base + (size_t)j1 * 768 + 512;
      const float* p2 = base + (size_t)j2 * 768 + 512;
      const float* p3 = base + (size_t)j3 * 768 + 512;
#pragma unroll
      for (int h = 0; h < 4; ++h) {
        acc[h] += __shfl(w[h], i + 0) * p0[h * DH + lane] +
                  __shfl(w[h], i + 1) * p1[h * DH + lane] +
                  __shfl(w[h], i + 2) * p2[h * DH + lane] +
                  __shfl(w[h], i + 3) * p3[h * DH + lane];
      }
    }
    for (; i < nn; ++i) {
      const float* p0 = base + (size_t)nbr[wv][i] * 768 + 512;
#pragma unroll
      for (int h = 0; h < 4; ++h) acc[h] += __shfl(w[h], i) * p0[h * DH + lane];
    }
#pragma unroll
    for (int h = 0; h < 4; ++h) acc[h] /= l[h];
  } else {
    float m[4] = {NEG_BIG, NEG_BIG, NEG_BIG, NEG_BIG};
    for (int i0 = 0; i0 < nn; i0 += 64) {
      float s[4] = {NEG_BIG, NEG_BIG, NEG_BIG, NEG_BIG};
      if (i0 + lane < nn) score4(nbr[wv][i0 + lane], s);
#pragma unroll
      for (int h = 0; h < 4; ++h) m[h] = fmaxf(m[h], s[h]);
    }
#pragma unroll
    for (int h = 0; h < 4; ++h) {
      for (int off = 32; off; off >>= 1) m[h] = fmaxf(m[h], __shfl_down(m[h], off));
      m[h] = __shfl(m[h], 0);
    }
    float l[4] = {0.f, 0.f, 0.f, 0.f};
    for (int i0 = 0; i0 < nn; i0 += 64) {
      float s[4] = {NEG_BIG, NEG_BIG, NEG_BIG, NEG_BIG};
      if (i0 + lane < nn) score4(nbr[wv][i0 + lane], s);
      float e[4];
#pragma unroll
      for (int h = 0; h < 4; ++h) {
        e[h] = (i0 + lane < nn) ? __expf(s[h] - m[h]) : 0.f;
        float ls = e[h];
        for (int off = 32; off; off >>= 1) ls += __shfl_down(ls, off);
        l[h] += __shfl(ls, 0);
      }
      int lim = min(64, nn - i0);
      for (int ii = 0; ii < lim; ++ii) {
        const float* p0 = base + (size_t)nbr[wv][i0 + ii] * 768 + 512;
#pragma unroll
        for (int h = 0; h < 4; ++h) acc[h] += __shfl(e[h], ii) * p0[h * DH + lane];
      }
    }
#pragma unroll
    for (int h = 0; h < 4; ++h) acc[h] /= l[h];
  }
#pragma unroll
  for (int h = 0; h < 4; ++h) {
    float a = acc[h];
    bf16 hi = (bf16)a;
    aos[(size_t)bn * 512 + h * DH + lane] = hi;
    aos[(size_t)bn * 512 + 256 + h * DH + lane] = (bf16)(a - (float)hi);
  }
}

// ---------------------------------------------------------------------------
// epilogue: u = x + proj + bo; out = LN(u)*gamma + beta
// ---------------------------------------------------------------------------
__global__ __launch_bounds__(64) void ln_kernel(const float* __restrict__ x,
                                                const float* __restrict__ proj,
                                                const float* __restrict__ bo,
                                                const float* __restrict__ gamma,
                                                const float* __restrict__ beta,
                                                float* __restrict__ out) {
  int row = blockIdx.x;
  int lane = threadIdx.x;
  size_t base = (size_t)row * D + lane * 4;
  float4 xv = *(const float4*)(x + base);
  float4 pv = *(const float4*)(proj + base);
  float4 bv = *(const float4*)(bo + lane * 4);
  float u0 = xv.x + pv.x + bv.x, u1 = xv.y + pv.y + bv.y;
  float u2 = xv.z + pv.z + bv.z, u3 = xv.w + pv.w + bv.w;
  float s = u0 + u1 + u2 + u3;
  for (int off = 32; off; off >>= 1) s += __shfl_down(s, off);
  s = __shfl(s, 0);
  float mean = s * (1.0f / D);
  float d0 = u0 - mean, d1 = u1 - mean, d2 = u2 - mean, d3 = u3 - mean;
  float ss = d0 * d0 + d1 * d1 + d2 * d2 + d3 * d3;
  for (int off = 32; off; off >>= 1) ss += __shfl_down(ss, off);
  ss = __shfl(ss, 0);
  float rstd = rsqrtf(ss * (1.0f / D) + 1e-5f);
  float4 gv = *(const float4*)(gamma + lane * 4);
  float4 be = *(const float4*)(beta + lane * 4);
  float4 o;
  o.x = d0 * rstd * gv.x + be.x;
  o.y = d1 * rstd * gv.y + be.y;
  o.z = d2 * rstd * gv.z + be.z;
  o.w = d3 * rstd * gv.w + be.w;
  *(float4*)(out + base) = o;
}

// ---------------------------------------------------------------------------
// Workspace.  Common: XsN [0,12.58M) | sim [12.58M,79.69M) | norms@79.69M
//                     mask@79.99M | Wt@82.08M (ends 83,132,416)
// BIG (ws >= 125,075,456; fill evidence says 256 MiB): qkv@83.13M |
//   aos@108.30M | proj@116.69M — alias-free -> fused sim+qkv dispatch.
// SMALL (>= 83,132,416, round-3-proven): qkv@12.58M, aos@37.75M,
//   proj@46.14M (inside dead sim region, written after topk).
// ---------------------------------------------------------------------------
extern "C" void kernel_launch(void* const* d_in, const int* in_sizes, int n_in,
                              void* d_out, int out_size, void* d_ws, size_t ws_size,
                              hipStream_t stream) {
  const float* x     = (const float*)d_in[0];
  const float* Wq    = (const float*)d_in[1];
  const float* Wk    = (const float*)d_in[2];
  const float* Wv    = (const float*)d_in[3];
  const float* Wo    = (const float*)d_in[4];
  const float* bo    = (const float*)d_in[5];
  const float* gamma = (const float*)d_in[6];
  const float* beta  = (const float*)d_in[7];
  float* out = (float*)d_out;

  char* ws = (char*)d_ws;
  bf16* XsN      = (bf16*)(ws);
  float* sim     = (float*)(ws + 12582912);
  float* norms   = (float*)(ws + 79691776);
  unsigned* mask = (unsigned*)(ws + 79986688);
  bf16* Wt       = (bf16*)(ws + 82083840);

  bool big = ws_size >= (size_t)125075456;
  float* qkv  = (float*)(ws + (big ? 83132416  : 12582912));
  bf16* aos   = (bf16*)(ws + (big ? 108298240 : 37748736));
  float* proj = (float*)(ws + (big ? 116686848 : 46137344));

  // 3-chunk sim split: hh + hm + mh.  2-chunk proj/qkv split: hh + mh.
  const int AMAP_SIM = PK6(0, 0, 1, 0, 0, 0);
  const int BMAP_SIM = PK6(0, 1, 0, 0, 0, 0);
  const int AMAP_2T  = PK3(0, 1, 0);
  const int BMAP_2T  = PK3(0, 0, 1);

  prep_kernel<<<9344, 64, 0, stream>>>(x, Wq, Wk, Wv, Wo, XsN, Wt, norms,
                                       (uint4*)mask);

  if (big) {
    gemm_fused_kernel<<<928, 256, 0, stream>>>(
        XsN, sim, AMAP_SIM, BMAP_SIM, Wt, qkv, AMAP_2T, BMAP_2T, norms);
    topk_adj_kernel<<<BATCH * N, 64, 0, stream>>>(sim, mask);
  } else {
    gemm_sim_kernel<<<544, 256, 0, stream>>>(XsN, sim, AMAP_SIM, BMAP_SIM);
    topk_adj_kernel<<<BATCH * N, 64, 0, stream>>>(sim, mask);
    gemm_gen_kernel<<<dim3(6, 64), 256, 0, stream>>>(
        XsN, Wt, qkv, 768, 512, 768, 8, AMAP_2T, BMAP_2T, norms);
  }

  attn_kernel<<<(BATCH * N) / 4, 256, 0, stream>>>(qkv, mask, aos);

  gemm_gen_kernel<<<dim3(2, 64), 256, 0, stream>>>(
      aos, Wt + (size_t)768 * 512, proj, 512, 512, D, 8, AMAP_2T, BMAP_2T, nullptr);
  ln_kernel<<<BATCH * N, 64, 0, stream>>>(x, proj, bo, gamma, beta, out);
}